// Round 2
// baseline (423.497 us; speedup 1.0000x reference)
//
#include <hip/hip_runtime.h>
#include <stdint.h>

typedef unsigned short u16;
typedef short short8 __attribute__((ext_vector_type(8)));
typedef float f32x4 __attribute__((ext_vector_type(4)));

#define S_LEN 2048
#define NQH 32
#define NKH 8
#define DHD 64

__device__ __forceinline__ float b2f(u16 u){
  union { uint32_t i; float f; } c; c.i = ((uint32_t)u) << 16; return c.f;
}
__device__ __forceinline__ u16 f2b(float f){
  union { float f; uint32_t i; } c; c.f = f;
  uint32_t r = c.i + 0x7fffu + ((c.i >> 16) & 1u);
  return (u16)(r >> 16);
}
__device__ __forceinline__ void gload_lds16(const void* g, void* l){
  __builtin_amdgcn_global_load_lds((const __attribute__((address_space(1))) uint32_t*)g,
                                   (__attribute__((address_space(3))) uint32_t*)l, 16, 0, 0);
}

// ---------------- fp32 -> bf16 convert ----------------
__global__ __launch_bounds__(256) void cvt_f32_bf16(const float* __restrict__ in,
                                                    u16* __restrict__ out, int n4){
  int i = blockIdx.x * 256 + threadIdx.x;
  if (i >= n4) return;
  float4 v = ((const float4*)in)[i];
  uint2 o;
  o.x = (uint32_t)f2b(v.x) | ((uint32_t)f2b(v.y) << 16);
  o.y = (uint32_t)f2b(v.z) | ((uint32_t)f2b(v.w) << 16);
  ((uint2*)out)[i] = o;
}

// ---------------- bf16 GEMM: C[M][N] = A[M][K] * B[N][K]^T ----------------
template<int OUT_F32>
__global__ __launch_bounds__(256)
void gemm_bt(const u16* __restrict__ A, const u16* __restrict__ Bm,
             void* __restrict__ Cp, int N, int K)
{
  __shared__ alignas(16) u16 lA[128 * 64];
  __shared__ alignas(16) u16 lB[128 * 64];
  const int tid = threadIdx.x;
  const int w = tid >> 6, l = tid & 63;
  const int lg = l >> 4, lc = l & 15;
  const int wm = w >> 1, wn = w & 1;
  const int m0 = blockIdx.y * 128, n0 = blockIdx.x * 128;
  const int srow = l >> 3, sc = l & 7;
  const size_t ldb = (size_t)K * 2;   // row bytes
  f32x4 acc[4][4] = {};
  const int kiters = K >> 6;
  for (int kt = 0; kt < kiters; ++kt){
    __syncthreads();
#pragma unroll
    for (int i = 0; i < 4; ++i){
      const int row = (i * 4 + w) * 8 + srow;
      const int gc = ((sc ^ (row & 7)) << 4);
      gload_lds16((const char*)A + (size_t)(m0 + row) * ldb + (size_t)kt * 128 + gc,
                  (char*)lA + row * 128 + sc * 16);
    }
#pragma unroll
    for (int i = 0; i < 4; ++i){
      const int row = (i * 4 + w) * 8 + srow;
      const int gc = ((sc ^ (row & 7)) << 4);
      gload_lds16((const char*)Bm + (size_t)(n0 + row) * ldb + (size_t)kt * 128 + gc,
                  (char*)lB + row * 128 + sc * 16);
    }
    __syncthreads();
#pragma unroll
    for (int kk = 0; kk < 2; ++kk){
      short8 af[4], bfr[4];
#pragma unroll
      for (int mi = 0; mi < 4; ++mi){
        const int row = wm * 64 + mi * 16 + lc;
        const int cc = (kk * 4 + lg) ^ (row & 7);
        af[mi] = *(const short8*)((const char*)lA + row * 128 + cc * 16);
      }
#pragma unroll
      for (int ni = 0; ni < 4; ++ni){
        const int row = wn * 64 + ni * 16 + lc;
        const int cc = (kk * 4 + lg) ^ (row & 7);
        bfr[ni] = *(const short8*)((const char*)lB + row * 128 + cc * 16);
      }
#pragma unroll
      for (int mi = 0; mi < 4; ++mi)
#pragma unroll
        for (int ni = 0; ni < 4; ++ni)
          acc[mi][ni] = __builtin_amdgcn_mfma_f32_16x16x32_bf16(af[mi], bfr[ni], acc[mi][ni], 0, 0, 0);
    }
  }
  const int r0 = m0 + wm * 64 + lg * 4;
  const int c0 = n0 + wn * 64 + lc;
#pragma unroll
  for (int mi = 0; mi < 4; ++mi)
#pragma unroll
    for (int ni = 0; ni < 4; ++ni)
#pragma unroll
      for (int j = 0; j < 4; ++j){
        const size_t idx = (size_t)(r0 + mi * 16 + j) * (size_t)N + (size_t)(c0 + ni * 16);
        if (OUT_F32) ((float*)Cp)[idx] = acc[mi][ni][j];
        else         ((u16*)Cp)[idx]  = f2b(acc[mi][ni][j]);
      }
}

// ---------------- RoPE + scales; qkv[b][s][48][64] -> Q[b][h][s][64], K[b][kh][s][64] ----------------
__global__ __launch_bounds__(256)
void rope_kernel(const u16* __restrict__ qkv, const float* __restrict__ cosT,
                 const float* __restrict__ sinT, const float* __restrict__ phs,
                 u16* __restrict__ Qo, u16* __restrict__ Ko)
{
  int id = blockIdx.x * 256 + threadIdx.x;      // B*40*S*4 = 655360
  int b = (id >= 327680) ? 1 : 0;
  int rem = id - b * 327680;
  int head = rem >> 13;                         // 0..39
  int s = (rem >> 2) & 2047;
  int d0 = (rem & 3) << 4;                      // 0,16,32,48
  const u16* src = qkv + (((size_t)(b * S_LEN + s) * 48 + head) << 6);
  uint4 xa = *(const uint4*)(src + d0);
  uint4 xb = *(const uint4*)(src + d0 + 8);
  int d0p = (d0 + 32) & 63;
  uint4 pa = *(const uint4*)(src + d0p);
  uint4 pb = *(const uint4*)(src + d0p + 8);
  const float* cp = cosT + s * 64 + d0;
  const float* sp = sinT + s * 64 + d0;
  const float sgn = (d0 < 32) ? -1.f : 1.f;
  const float scale = 1.2f * (head < NQH ? phs[b * NQH + head] : 1.f);
  uint32_t xs[4] = {xa.x, xa.y, xa.z, xa.w};
  uint32_t xs2[4] = {xb.x, xb.y, xb.z, xb.w};
  uint32_t ps[4] = {pa.x, pa.y, pa.z, pa.w};
  uint32_t ps2[4] = {pb.x, pb.y, pb.z, pb.w};
  uint32_t ow[8];
#pragma unroll
  for (int k = 0; k < 4; ++k){
    float v0 = b2f((u16)(xs[k] & 0xffff)) * cp[2*k]   + sgn * b2f((u16)(ps[k] & 0xffff)) * sp[2*k];
    float v1 = b2f((u16)(xs[k] >> 16))    * cp[2*k+1] + sgn * b2f((u16)(ps[k] >> 16))    * sp[2*k+1];
    ow[k] = (uint32_t)f2b(v0 * scale) | ((uint32_t)f2b(v1 * scale) << 16);
  }
#pragma unroll
  for (int k = 0; k < 4; ++k){
    float v0 = b2f((u16)(xs2[k] & 0xffff)) * cp[8+2*k]   + sgn * b2f((u16)(ps2[k] & 0xffff)) * sp[8+2*k];
    float v1 = b2f((u16)(xs2[k] >> 16))    * cp[8+2*k+1] + sgn * b2f((u16)(ps2[k] >> 16))    * sp[8+2*k+1];
    ow[4+k] = (uint32_t)f2b(v0 * scale) | ((uint32_t)f2b(v1 * scale) << 16);
  }
  u16* dst;
  if (head < NQH) dst = Qo + (((size_t)(b * NQH + head) * S_LEN + s) << 6) + d0;
  else            dst = Ko + (((size_t)(b * NKH + head - NQH) * S_LEN + s) << 6) + d0;
  uint4 o0 = {ow[0], ow[1], ow[2], ow[3]};
  uint4 o1 = {ow[4], ow[5], ow[6], ow[7]};
  *(uint4*)dst = o0;
  *(uint4*)(dst + 8) = o1;
}

// ---------------- V transpose: qkv v-heads -> VT[b][kh][d][s] ----------------
__global__ __launch_bounds__(256)
void vtrans(const u16* __restrict__ qkv, u16* __restrict__ VT)
{
  int bid = blockIdx.x;                 // (b*8+kh)*32 + st
  int st = bid & 31, kh = (bid >> 5) & 7, b = bid >> 8;
  __shared__ alignas(16) u16 t[64][72];
  int tid = threadIdx.x;
  int r = tid >> 2, c4 = tid & 3;
  const u16* src = qkv + (((size_t)(b * S_LEN + st * 64 + r) * 48 + 40 + kh) << 6) + c4 * 16;
  *(uint4*)&t[r][c4 * 16]     = *(const uint4*)src;
  *(uint4*)&t[r][c4 * 16 + 8] = *(const uint4*)(src + 8);
  __syncthreads();
  u16 o[16];
#pragma unroll
  for (int i = 0; i < 16; ++i) o[i] = t[c4 * 16 + i][r];   // r = d row now
  u16* dst = VT + ((size_t)(b * NKH + kh) * 64 + r) * S_LEN + st * 64 + c4 * 16;
  uint4 o0 = { (uint32_t)o[0] | ((uint32_t)o[1] << 16),  (uint32_t)o[2] | ((uint32_t)o[3] << 16),
               (uint32_t)o[4] | ((uint32_t)o[5] << 16),  (uint32_t)o[6] | ((uint32_t)o[7] << 16) };
  uint4 o1 = { (uint32_t)o[8] | ((uint32_t)o[9] << 16),  (uint32_t)o[10] | ((uint32_t)o[11] << 16),
               (uint32_t)o[12] | ((uint32_t)o[13] << 16),(uint32_t)o[14] | ((uint32_t)o[15] << 16) };
  *(uint4*)dst = o0;
  *(uint4*)(dst + 8) = o1;
}

// ---------------- causal GQA flash attention, complement-paired ----------------
// block: (b, kh, g, pair p). Two 64-row q-chunks: qlo=p, qhi=31-p (64-row tile
// units). KV tiles t=0..qhi staged once; chunk lo active while t<=qlo.
// Per-block compute = (qlo+1)+(qhi+1) = 33 tile-units for EVERY block.
__global__ __launch_bounds__(256, 4)
void attn_kernel(const u16* __restrict__ Q, const u16* __restrict__ Kr,
                 const u16* __restrict__ VT, u16* __restrict__ Ao)
{
  int bid = blockIdx.x;
  int p  = bid & 15;
  int g  = (bid >> 4) & 3;
  int kh = (bid >> 6) & 7;
  int b  = bid >> 9;
  int h = kh * 4 + g;
  const int qt0 = p, qt1 = 31 - p;     // chunk tile indices (64-row units)

  __shared__ alignas(16) u16 lK[64 * 64];        // [j][d], swizzled
  __shared__ alignas(16) u16 lV[64 * 64];        // [d][j], swizzled
  __shared__ alignas(16) u16 lP[4][2][16][64];   // [wave][chunk][row][col], XOR-swizzled

  const int tid = threadIdx.x;
  const int w = tid >> 6, l = tid & 63;
  const int lg = l >> 4, lc = l & 15;
  const int srow = l >> 3, sc = l & 7;

  const float kscale = 0.18033688011112042f;     // SM_SCALE * log2(e)

  // Q fragments for both chunks: rows qt*64 + w*16 + lc, k = kk*32 + lg*8
  short8 qf[2][2];
  {
    const u16* qbase = Q + ((size_t)(b * NQH + h) * S_LEN) * 64;
#pragma unroll
    for (int kk = 0; kk < 2; ++kk){
      qf[0][kk] = *(const short8*)(qbase + (size_t)(qt0 * 64 + w * 16 + lc) * 64 + kk * 32 + lg * 8);
      qf[1][kk] = *(const short8*)(qbase + (size_t)(qt1 * 64 + w * 16 + lc) * 64 + kk * 32 + lg * 8);
    }
  }

  const u16* Kb = Kr + (size_t)(b * NKH + kh) * S_LEN * 64;
  const u16* Vb = VT + (size_t)(b * NKH + kh) * 64 * S_LEN;

  f32x4 o[2][4] = {};
  f32x4 mrow[2], lsum[2];
#pragma unroll
  for (int c = 0; c < 2; ++c)
#pragma unroll
    for (int j = 0; j < 4; ++j){ mrow[c][j] = -3.0e38f; lsum[c][j] = 0.f; }

  const int ntiles = qt1 + 1;
  for (int t = 0; t < ntiles; ++t){
    const bool act0 = (t <= qt0);
    __syncthreads();
#pragma unroll
    for (int i = 0; i < 2; ++i){
      const int row = (i * 4 + w) * 8 + srow;
      const int gc = ((sc ^ (row & 7)) << 4);
      gload_lds16((const char*)(Kb + (size_t)(t * 64 + row) * 64) + gc,
                  (char*)lK + row * 128 + sc * 16);
    }
#pragma unroll
    for (int i = 0; i < 2; ++i){
      const int row = (i * 4 + w) * 8 + srow;
      const int gc = ((sc ^ (row & 7)) << 4);
      gload_lds16((const char*)(Vb + (size_t)row * S_LEN + t * 64) + gc,
                  (char*)lV + row * 128 + sc * 16);
    }
    __syncthreads();

    // S = Q K^T for active chunks
    f32x4 sv[2][4] = {};
#pragma unroll
    for (int kk = 0; kk < 2; ++kk){
      short8 kf[4];
#pragma unroll
      for (int nj = 0; nj < 4; ++nj){
        const int row = nj * 16 + lc;
        const int cc = (kk * 4 + lg) ^ (row & 7);
        kf[nj] = *(const short8*)((const char*)lK + row * 128 + cc * 16);
      }
      if (act0)
#pragma unroll
        for (int nj = 0; nj < 4; ++nj)
          sv[0][nj] = __builtin_amdgcn_mfma_f32_16x16x32_bf16(qf[0][kk], kf[nj], sv[0][nj], 0, 0, 0);
#pragma unroll
      for (int nj = 0; nj < 4; ++nj)
        sv[1][nj] = __builtin_amdgcn_mfma_f32_16x16x32_bf16(qf[1][kk], kf[nj], sv[1][nj], 0, 0, 0);
    }

    // online softmax per chunk (exp2 domain)
#pragma unroll
    for (int c = 0; c < 2; ++c){
      if (c == 0 && !act0) continue;
      const int qt = c ? qt1 : qt0;
      const int rbase = qt * 64 + w * 16 + lg * 4;
      if (t == qt){            // diagonal tile: scale + causal mask
#pragma unroll
        for (int nj = 0; nj < 4; ++nj){
          const int col = t * 64 + nj * 16 + lc;
#pragma unroll
          for (int j = 0; j < 4; ++j){
            float v = sv[c][nj][j] * kscale;
            sv[c][nj][j] = (col <= rbase + j) ? v : -3.0e38f;
          }
        }
      } else {                 // fully visible tile: scale only
#pragma unroll
        for (int nj = 0; nj < 4; ++nj)
#pragma unroll
          for (int j = 0; j < 4; ++j)
            sv[c][nj][j] *= kscale;
      }
      f32x4 pmax;
#pragma unroll
      for (int j = 0; j < 4; ++j)
        pmax[j] = fmaxf(fmaxf(sv[c][0][j], sv[c][1][j]), fmaxf(sv[c][2][j], sv[c][3][j]));
#pragma unroll
      for (int off = 1; off < 16; off <<= 1)
#pragma unroll
        for (int j = 0; j < 4; ++j)
          pmax[j] = fmaxf(pmax[j], __shfl_xor(pmax[j], off));
      f32x4 mnew, sf;
#pragma unroll
      for (int j = 0; j < 4; ++j){
        mnew[j] = fmaxf(mrow[c][j], pmax[j]);
        sf[j] = __builtin_amdgcn_exp2f(mrow[c][j] - mnew[j]);
        mrow[c][j] = mnew[j];
      }
      f32x4 psum = {0.f, 0.f, 0.f, 0.f};
#pragma unroll
      for (int nj = 0; nj < 4; ++nj)
#pragma unroll
        for (int j = 0; j < 4; ++j){
          float pv = __builtin_amdgcn_exp2f(sv[c][nj][j] - mnew[j]);
          sv[c][nj][j] = pv;
          psum[j] += pv;
        }
#pragma unroll
      for (int off = 1; off < 16; off <<= 1)
#pragma unroll
        for (int j = 0; j < 4; ++j)
          psum[j] += __shfl_xor(psum[j], off);
#pragma unroll
      for (int j = 0; j < 4; ++j)
        lsum[c][j] = lsum[c][j] * sf[j] + psum[j];
#pragma unroll
      for (int dn = 0; dn < 4; ++dn)
#pragma unroll
        for (int j = 0; j < 4; ++j)
          o[c][dn][j] *= sf[j];
      // P -> per-wave LDS (bf16); rows lg*4+j, 8-col chunk XOR-swizzled by row
#pragma unroll
      for (int nj = 0; nj < 4; ++nj)
#pragma unroll
        for (int j = 0; j < 4; ++j){
          const int row = lg * 4 + j;
          const int ci = (nj * 2 + (lc >> 3)) ^ (row & 7);
          lP[w][c][row][ci * 8 + (lc & 7)] = f2b(sv[c][nj][j]);
        }
    }

    // O += P V
#pragma unroll
    for (int kk2 = 0; kk2 < 2; ++kk2){
      short8 vf[4];
#pragma unroll
      for (int dn = 0; dn < 4; ++dn){
        const int row = dn * 16 + lc;
        const int cc = (kk2 * 4 + lg) ^ (row & 7);
        vf[dn] = *(const short8*)((const char*)lV + row * 128 + cc * 16);
      }
#pragma unroll
      for (int c = 0; c < 2; ++c){
        if (c == 0 && !act0) continue;
        const short8 pa = *(const short8*)&lP[w][c][lc][(((kk2 * 4 + lg) ^ (lc & 7))) * 8];
#pragma unroll
        for (int dn = 0; dn < 4; ++dn)
          o[c][dn] = __builtin_amdgcn_mfma_f32_16x16x32_bf16(pa, vf[dn], o[c][dn], 0, 0, 0);
      }
    }
  }

  // epilogue: normalize + write attn_out[b][s][h*64+d] (bf16)
#pragma unroll
  for (int c = 0; c < 2; ++c){
    const int qt = c ? qt1 : qt0;
    f32x4 inv;
#pragma unroll
    for (int j = 0; j < 4; ++j) inv[j] = 1.f / lsum[c][j];
#pragma unroll
    for (int dn = 0; dn < 4; ++dn)
#pragma unroll
      for (int j = 0; j < 4; ++j){
        const int row = qt * 64 + w * 16 + lg * 4 + j;
        const int col = h * 64 + dn * 16 + lc;
        Ao[(size_t)(b * S_LEN + row) * 2048 + col] = f2b(o[c][dn][j] * inv[j]);
      }
  }
}

// ---------------- launcher ----------------
extern "C" void kernel_launch(void* const* d_in, const int* in_sizes, int n_in,
                              void* d_out, int out_size, void* d_ws, size_t ws_size,
                              hipStream_t stream)
{
  const float* cosT = (const float*)d_in[0];
  const float* sinT = (const float*)d_in[1];
  const float* hs   = (const float*)d_in[2];
  const float* phs  = (const float*)d_in[3];
  const float* Wqkv = (const float*)d_in[4];
  const float* Wo   = (const float*)d_in[5];
  float* out = (float*)d_out;
  char* ws = (char*)d_ws;

  u16* hsB   = (u16*)(ws);               // 16,777,216 B (aliased as attn_out later)
  u16* WqkvB = (u16*)(ws + 16777216);    // 12,582,912 B
  u16* WoB   = (u16*)(ws + 29360128);    //  8,388,608 B
  u16* qkvB  = (u16*)(ws + 37748736);    // 25,165,824 B
  u16* Qb    = (u16*)(ws + 62914560);    // 16,777,216 B
  u16* Kb    = (u16*)(ws + 79691776);    //  4,194,304 B
  u16* VTb   = (u16*)(ws + 83886080);    //  4,194,304 B  (total 88,080,384 B)
  u16* Ao    = hsB;                      // hsB dead after GEMM1

  cvt_f32_bf16<<<8192, 256, 0, stream>>>(hs,   hsB,   2097152);
  cvt_f32_bf16<<<6144, 256, 0, stream>>>(Wqkv, WqkvB, 1572864);
  cvt_f32_bf16<<<4096, 256, 0, stream>>>(Wo,   WoB,   1048576);
  gemm_bt<0><<<dim3(24, 32), 256, 0, stream>>>(hsB, WqkvB, (void*)qkvB, 3072, 2048);
  rope_kernel<<<2560, 256, 0, stream>>>(qkvB, cosT, sinT, phs, Qb, Kb);
  vtrans<<<512, 256, 0, stream>>>(qkvB, VTb);
  attn_kernel<<<1024, 256, 0, stream>>>(Qb, Kb, VTb, Ao);
  gemm_bt<1><<<dim3(16, 32), 256, 0, stream>>>(Ao, WoB, (void*)out, 2048, 2048);
}

// Round 3
// 286.059 us; speedup vs baseline: 1.4804x; 1.4804x over previous
//
#include <hip/hip_runtime.h>
#include <stdint.h>

typedef unsigned short u16;
typedef short short8 __attribute__((ext_vector_type(8)));
typedef float f32x4 __attribute__((ext_vector_type(4)));

#define S_LEN 2048
#define NQH 32
#define NKH 8
#define DHD 64

__device__ __forceinline__ float b2f(u16 u){
  union { uint32_t i; float f; } c; c.i = ((uint32_t)u) << 16; return c.f;
}
__device__ __forceinline__ u16 f2b(float f){
  union { float f; uint32_t i; } c; c.f = f;
  uint32_t r = c.i + 0x7fffu + ((c.i >> 16) & 1u);
  return (u16)(r >> 16);
}
__device__ __forceinline__ void gload_lds16(const void* g, void* l){
  __builtin_amdgcn_global_load_lds((const __attribute__((address_space(1))) uint32_t*)g,
                                   (__attribute__((address_space(3))) uint32_t*)l, 16, 0, 0);
}

// ---------------- fp32 -> bf16 convert ----------------
__global__ __launch_bounds__(256) void cvt_f32_bf16(const float* __restrict__ in,
                                                    u16* __restrict__ out, int n4){
  int i = blockIdx.x * 256 + threadIdx.x;
  if (i >= n4) return;
  float4 v = ((const float4*)in)[i];
  uint2 o;
  o.x = (uint32_t)f2b(v.x) | ((uint32_t)f2b(v.y) << 16);
  o.y = (uint32_t)f2b(v.z) | ((uint32_t)f2b(v.w) << 16);
  ((uint2*)out)[i] = o;
}

// ---------------- bf16 GEMM: C[M][N] = A[M][K] * B[N][K]^T ----------------
template<int OUT_F32>
__global__ __launch_bounds__(256)
void gemm_bt(const u16* __restrict__ A, const u16* __restrict__ Bm,
             void* __restrict__ Cp, int N, int K)
{
  __shared__ alignas(16) u16 lA[128 * 64];
  __shared__ alignas(16) u16 lB[128 * 64];
  const int tid = threadIdx.x;
  const int w = tid >> 6, l = tid & 63;
  const int lg = l >> 4, lc = l & 15;
  const int wm = w >> 1, wn = w & 1;
  const int m0 = blockIdx.y * 128, n0 = blockIdx.x * 128;
  const int srow = l >> 3, sc = l & 7;
  const size_t ldb = (size_t)K * 2;   // row bytes
  f32x4 acc[4][4] = {};
  const int kiters = K >> 6;
  for (int kt = 0; kt < kiters; ++kt){
    __syncthreads();
#pragma unroll
    for (int i = 0; i < 4; ++i){
      const int row = (i * 4 + w) * 8 + srow;
      const int gc = ((sc ^ (row & 7)) << 4);
      gload_lds16((const char*)A + (size_t)(m0 + row) * ldb + (size_t)kt * 128 + gc,
                  (char*)lA + row * 128 + sc * 16);
    }
#pragma unroll
    for (int i = 0; i < 4; ++i){
      const int row = (i * 4 + w) * 8 + srow;
      const int gc = ((sc ^ (row & 7)) << 4);
      gload_lds16((const char*)Bm + (size_t)(n0 + row) * ldb + (size_t)kt * 128 + gc,
                  (char*)lB + row * 128 + sc * 16);
    }
    __syncthreads();
#pragma unroll
    for (int kk = 0; kk < 2; ++kk){
      short8 af[4], bfr[4];
#pragma unroll
      for (int mi = 0; mi < 4; ++mi){
        const int row = wm * 64 + mi * 16 + lc;
        const int cc = (kk * 4 + lg) ^ (row & 7);
        af[mi] = *(const short8*)((const char*)lA + row * 128 + cc * 16);
      }
#pragma unroll
      for (int ni = 0; ni < 4; ++ni){
        const int row = wn * 64 + ni * 16 + lc;
        const int cc = (kk * 4 + lg) ^ (row & 7);
        bfr[ni] = *(const short8*)((const char*)lB + row * 128 + cc * 16);
      }
#pragma unroll
      for (int mi = 0; mi < 4; ++mi)
#pragma unroll
        for (int ni = 0; ni < 4; ++ni)
          acc[mi][ni] = __builtin_amdgcn_mfma_f32_16x16x32_bf16(af[mi], bfr[ni], acc[mi][ni], 0, 0, 0);
    }
  }
  const int r0 = m0 + wm * 64 + lg * 4;
  const int c0 = n0 + wn * 64 + lc;
#pragma unroll
  for (int mi = 0; mi < 4; ++mi)
#pragma unroll
    for (int ni = 0; ni < 4; ++ni)
#pragma unroll
      for (int j = 0; j < 4; ++j){
        const size_t idx = (size_t)(r0 + mi * 16 + j) * (size_t)N + (size_t)(c0 + ni * 16);
        if (OUT_F32) ((float*)Cp)[idx] = acc[mi][ni][j];
        else         ((u16*)Cp)[idx]  = f2b(acc[mi][ni][j]);
      }
}

// ---------------- RoPE + scales; qkv[b][s][48][64] -> Q[b][h][s][64], K[b][kh][s][64] ----------------
__global__ __launch_bounds__(256)
void rope_kernel(const u16* __restrict__ qkv, const float* __restrict__ cosT,
                 const float* __restrict__ sinT, const float* __restrict__ phs,
                 u16* __restrict__ Qo, u16* __restrict__ Ko)
{
  int id = blockIdx.x * 256 + threadIdx.x;      // B*40*S*4 = 655360
  int b = (id >= 327680) ? 1 : 0;
  int rem = id - b * 327680;
  int head = rem >> 13;                         // 0..39
  int s = (rem >> 2) & 2047;
  int d0 = (rem & 3) << 4;                      // 0,16,32,48
  const u16* src = qkv + (((size_t)(b * S_LEN + s) * 48 + head) << 6);
  uint4 xa = *(const uint4*)(src + d0);
  uint4 xb = *(const uint4*)(src + d0 + 8);
  int d0p = (d0 + 32) & 63;
  uint4 pa = *(const uint4*)(src + d0p);
  uint4 pb = *(const uint4*)(src + d0p + 8);
  const float* cp = cosT + s * 64 + d0;
  const float* sp = sinT + s * 64 + d0;
  const float sgn = (d0 < 32) ? -1.f : 1.f;
  const float scale = 1.2f * (head < NQH ? phs[b * NQH + head] : 1.f);
  uint32_t xs[4] = {xa.x, xa.y, xa.z, xa.w};
  uint32_t xs2[4] = {xb.x, xb.y, xb.z, xb.w};
  uint32_t ps[4] = {pa.x, pa.y, pa.z, pa.w};
  uint32_t ps2[4] = {pb.x, pb.y, pb.z, pb.w};
  uint32_t ow[8];
#pragma unroll
  for (int k = 0; k < 4; ++k){
    float v0 = b2f((u16)(xs[k] & 0xffff)) * cp[2*k]   + sgn * b2f((u16)(ps[k] & 0xffff)) * sp[2*k];
    float v1 = b2f((u16)(xs[k] >> 16))    * cp[2*k+1] + sgn * b2f((u16)(ps[k] >> 16))    * sp[2*k+1];
    ow[k] = (uint32_t)f2b(v0 * scale) | ((uint32_t)f2b(v1 * scale) << 16);
  }
#pragma unroll
  for (int k = 0; k < 4; ++k){
    float v0 = b2f((u16)(xs2[k] & 0xffff)) * cp[8+2*k]   + sgn * b2f((u16)(ps2[k] & 0xffff)) * sp[8+2*k];
    float v1 = b2f((u16)(xs2[k] >> 16))    * cp[8+2*k+1] + sgn * b2f((u16)(ps2[k] >> 16))    * sp[8+2*k+1];
    ow[4+k] = (uint32_t)f2b(v0 * scale) | ((uint32_t)f2b(v1 * scale) << 16);
  }
  u16* dst;
  if (head < NQH) dst = Qo + (((size_t)(b * NQH + head) * S_LEN + s) << 6) + d0;
  else            dst = Ko + (((size_t)(b * NKH + head - NQH) * S_LEN + s) << 6) + d0;
  uint4 o0 = {ow[0], ow[1], ow[2], ow[3]};
  uint4 o1 = {ow[4], ow[5], ow[6], ow[7]};
  *(uint4*)dst = o0;
  *(uint4*)(dst + 8) = o1;
}

// ---------------- V transpose: qkv v-heads -> VT[b][kh][d][s] ----------------
__global__ __launch_bounds__(256)
void vtrans(const u16* __restrict__ qkv, u16* __restrict__ VT)
{
  int bid = blockIdx.x;                 // (b*8+kh)*32 + st
  int st = bid & 31, kh = (bid >> 5) & 7, b = bid >> 8;
  __shared__ alignas(16) u16 t[64][72];
  int tid = threadIdx.x;
  int r = tid >> 2, c4 = tid & 3;
  const u16* src = qkv + (((size_t)(b * S_LEN + st * 64 + r) * 48 + 40 + kh) << 6) + c4 * 16;
  *(uint4*)&t[r][c4 * 16]     = *(const uint4*)src;
  *(uint4*)&t[r][c4 * 16 + 8] = *(const uint4*)(src + 8);
  __syncthreads();
  u16 o[16];
#pragma unroll
  for (int i = 0; i < 16; ++i) o[i] = t[c4 * 16 + i][r];   // r = d row now
  u16* dst = VT + ((size_t)(b * NKH + kh) * 64 + r) * S_LEN + st * 64 + c4 * 16;
  uint4 o0 = { (uint32_t)o[0] | ((uint32_t)o[1] << 16),  (uint32_t)o[2] | ((uint32_t)o[3] << 16),
               (uint32_t)o[4] | ((uint32_t)o[5] << 16),  (uint32_t)o[6] | ((uint32_t)o[7] << 16) };
  uint4 o1 = { (uint32_t)o[8] | ((uint32_t)o[9] << 16),  (uint32_t)o[10] | ((uint32_t)o[11] << 16),
               (uint32_t)o[12] | ((uint32_t)o[13] << 16),(uint32_t)o[14] | ((uint32_t)o[15] << 16) };
  *(uint4*)dst = o0;
  *(uint4*)(dst + 8) = o1;
}

// ---------------- causal GQA flash attention, complement-paired ----------------
// block: (b, kh, g, pair p). Two 64-row q-chunks: qlo=p, qhi=31-p (64-row tile
// units). KV tiles t=0..qhi staged once; chunk lo active while t<=qlo.
// Per-block compute = 33 tile-units for EVERY block (perfect balance).
// launch_bounds(256,2): cap 256 VGPR — (256,4) forced 64 VGPR and spilled
// 149 MB/dispatch to scratch (R2 post-mortem).
__global__ __launch_bounds__(256, 2)
void attn_kernel(const u16* __restrict__ Q, const u16* __restrict__ Kr,
                 const u16* __restrict__ VT, u16* __restrict__ Ao)
{
  int bid = blockIdx.x;
  int p  = bid & 15;
  int g  = (bid >> 4) & 3;
  int kh = (bid >> 6) & 7;
  int b  = bid >> 9;
  int h = kh * 4 + g;
  const int qt0 = p, qt1 = 31 - p;     // chunk tile indices (64-row units)

  __shared__ alignas(16) u16 lK[64 * 64];        // [j][d], swizzled
  __shared__ alignas(16) u16 lV[64 * 64];        // [d][j], swizzled
  __shared__ alignas(16) u16 lP[4][2][16][64];   // [wave][chunk][row][col], XOR-swizzled

  const int tid = threadIdx.x;
  const int w = tid >> 6, l = tid & 63;
  const int lg = l >> 4, lc = l & 15;
  const int srow = l >> 3, sc = l & 7;

  const float kscale = 0.18033688011112042f;     // SM_SCALE * log2(e)

  // Q fragments for both chunks: rows qt*64 + w*16 + lc, k = kk*32 + lg*8
  short8 qf[2][2];
  {
    const u16* qbase = Q + ((size_t)(b * NQH + h) * S_LEN) * 64;
#pragma unroll
    for (int kk = 0; kk < 2; ++kk){
      qf[0][kk] = *(const short8*)(qbase + (size_t)(qt0 * 64 + w * 16 + lc) * 64 + kk * 32 + lg * 8);
      qf[1][kk] = *(const short8*)(qbase + (size_t)(qt1 * 64 + w * 16 + lc) * 64 + kk * 32 + lg * 8);
    }
  }

  const u16* Kb = Kr + (size_t)(b * NKH + kh) * S_LEN * 64;
  const u16* Vb = VT + (size_t)(b * NKH + kh) * 64 * S_LEN;

  f32x4 o[2][4] = {};
  f32x4 mrow[2], lsum[2];
#pragma unroll
  for (int c = 0; c < 2; ++c)
#pragma unroll
    for (int j = 0; j < 4; ++j){ mrow[c][j] = -3.0e38f; lsum[c][j] = 0.f; }

  const int ntiles = qt1 + 1;
  for (int t = 0; t < ntiles; ++t){
    const bool act0 = (t <= qt0);
    __syncthreads();
#pragma unroll
    for (int i = 0; i < 2; ++i){
      const int row = (i * 4 + w) * 8 + srow;
      const int gc = ((sc ^ (row & 7)) << 4);
      gload_lds16((const char*)(Kb + (size_t)(t * 64 + row) * 64) + gc,
                  (char*)lK + row * 128 + sc * 16);
    }
#pragma unroll
    for (int i = 0; i < 2; ++i){
      const int row = (i * 4 + w) * 8 + srow;
      const int gc = ((sc ^ (row & 7)) << 4);
      gload_lds16((const char*)(Vb + (size_t)row * S_LEN + t * 64) + gc,
                  (char*)lV + row * 128 + sc * 16);
    }
    __syncthreads();

    // S = Q K^T for active chunks
    f32x4 sv[2][4] = {};
#pragma unroll
    for (int kk = 0; kk < 2; ++kk){
      short8 kf[4];
#pragma unroll
      for (int nj = 0; nj < 4; ++nj){
        const int row = nj * 16 + lc;
        const int cc = (kk * 4 + lg) ^ (row & 7);
        kf[nj] = *(const short8*)((const char*)lK + row * 128 + cc * 16);
      }
      if (act0)
#pragma unroll
        for (int nj = 0; nj < 4; ++nj)
          sv[0][nj] = __builtin_amdgcn_mfma_f32_16x16x32_bf16(qf[0][kk], kf[nj], sv[0][nj], 0, 0, 0);
#pragma unroll
      for (int nj = 0; nj < 4; ++nj)
        sv[1][nj] = __builtin_amdgcn_mfma_f32_16x16x32_bf16(qf[1][kk], kf[nj], sv[1][nj], 0, 0, 0);
    }

    // online softmax per chunk (exp2 domain)
#pragma unroll
    for (int c = 0; c < 2; ++c){
      if (c == 0 && !act0) continue;
      const int qt = c ? qt1 : qt0;
      const int rbase = qt * 64 + w * 16 + lg * 4;
      if (t == qt){            // diagonal tile: scale + causal mask
#pragma unroll
        for (int nj = 0; nj < 4; ++nj){
          const int col = t * 64 + nj * 16 + lc;
#pragma unroll
          for (int j = 0; j < 4; ++j){
            float v = sv[c][nj][j] * kscale;
            sv[c][nj][j] = (col <= rbase + j) ? v : -3.0e38f;
          }
        }
      } else {                 // fully visible tile: scale only
#pragma unroll
        for (int nj = 0; nj < 4; ++nj)
#pragma unroll
          for (int j = 0; j < 4; ++j)
            sv[c][nj][j] *= kscale;
      }
      f32x4 pmax;
#pragma unroll
      for (int j = 0; j < 4; ++j)
        pmax[j] = fmaxf(fmaxf(sv[c][0][j], sv[c][1][j]), fmaxf(sv[c][2][j], sv[c][3][j]));
#pragma unroll
      for (int off = 1; off < 16; off <<= 1)
#pragma unroll
        for (int j = 0; j < 4; ++j)
          pmax[j] = fmaxf(pmax[j], __shfl_xor(pmax[j], off));
      f32x4 mnew, sf;
#pragma unroll
      for (int j = 0; j < 4; ++j){
        mnew[j] = fmaxf(mrow[c][j], pmax[j]);
        sf[j] = __builtin_amdgcn_exp2f(mrow[c][j] - mnew[j]);
        mrow[c][j] = mnew[j];
      }
      f32x4 psum = {0.f, 0.f, 0.f, 0.f};
#pragma unroll
      for (int nj = 0; nj < 4; ++nj)
#pragma unroll
        for (int j = 0; j < 4; ++j){
          float pv = __builtin_amdgcn_exp2f(sv[c][nj][j] - mnew[j]);
          sv[c][nj][j] = pv;
          psum[j] += pv;
        }
#pragma unroll
      for (int off = 1; off < 16; off <<= 1)
#pragma unroll
        for (int j = 0; j < 4; ++j)
          psum[j] += __shfl_xor(psum[j], off);
#pragma unroll
      for (int j = 0; j < 4; ++j)
        lsum[c][j] = lsum[c][j] * sf[j] + psum[j];
#pragma unroll
      for (int dn = 0; dn < 4; ++dn)
#pragma unroll
        for (int j = 0; j < 4; ++j)
          o[c][dn][j] *= sf[j];
      // P -> per-wave LDS (bf16); rows lg*4+j, 8-col chunk XOR-swizzled by row
#pragma unroll
      for (int nj = 0; nj < 4; ++nj)
#pragma unroll
        for (int j = 0; j < 4; ++j){
          const int row = lg * 4 + j;
          const int ci = (nj * 2 + (lc >> 3)) ^ (row & 7);
          lP[w][c][row][ci * 8 + (lc & 7)] = f2b(sv[c][nj][j]);
        }
    }

    // O += P V
#pragma unroll
    for (int kk2 = 0; kk2 < 2; ++kk2){
      short8 vf[4];
#pragma unroll
      for (int dn = 0; dn < 4; ++dn){
        const int row = dn * 16 + lc;
        const int cc = (kk2 * 4 + lg) ^ (row & 7);
        vf[dn] = *(const short8*)((const char*)lV + row * 128 + cc * 16);
      }
      const int pci = ((kk2 * 4 + lg) ^ (lc & 7)) * 8;
#pragma unroll
      for (int c = 0; c < 2; ++c){
        if (c == 0 && !act0) continue;
        const short8 pa = *(const short8*)&lP[w][c][lc][pci];
#pragma unroll
        for (int dn = 0; dn < 4; ++dn)
          o[c][dn] = __builtin_amdgcn_mfma_f32_16x16x32_bf16(pa, vf[dn], o[c][dn], 0, 0, 0);
      }
    }
  }

  // epilogue: normalize + write attn_out[b][s][h*64+d] (bf16)
#pragma unroll
  for (int c = 0; c < 2; ++c){
    const int qt = c ? qt1 : qt0;
    f32x4 inv;
#pragma unroll
    for (int j = 0; j < 4; ++j) inv[j] = 1.f / lsum[c][j];
#pragma unroll
    for (int dn = 0; dn < 4; ++dn)
#pragma unroll
      for (int j = 0; j < 4; ++j){
        const int row = qt * 64 + w * 16 + lg * 4 + j;
        const int col = h * 64 + dn * 16 + lc;
        Ao[(size_t)(b * S_LEN + row) * 2048 + col] = f2b(o[c][dn][j] * inv[j]);
      }
  }
}

// ---------------- launcher ----------------
extern "C" void kernel_launch(void* const* d_in, const int* in_sizes, int n_in,
                              void* d_out, int out_size, void* d_ws, size_t ws_size,
                              hipStream_t stream)
{
  const float* cosT = (const float*)d_in[0];
  const float* sinT = (const float*)d_in[1];
  const float* hs   = (const float*)d_in[2];
  const float* phs  = (const float*)d_in[3];
  const float* Wqkv = (const float*)d_in[4];
  const float* Wo   = (const float*)d_in[5];
  float* out = (float*)d_out;
  char* ws = (char*)d_ws;

  u16* hsB   = (u16*)(ws);               // 16,777,216 B (aliased as attn_out later)
  u16* WqkvB = (u16*)(ws + 16777216);    // 12,582,912 B
  u16* WoB   = (u16*)(ws + 29360128);    //  8,388,608 B
  u16* qkvB  = (u16*)(ws + 37748736);    // 25,165,824 B
  u16* Qb    = (u16*)(ws + 62914560);    // 16,777,216 B
  u16* Kb    = (u16*)(ws + 79691776);    //  4,194,304 B
  u16* VTb   = (u16*)(ws + 83886080);    //  4,194,304 B  (total 88,080,384 B)
  u16* Ao    = hsB;                      // hsB dead after GEMM1

  cvt_f32_bf16<<<8192, 256, 0, stream>>>(hs,   hsB,   2097152);
  cvt_f32_bf16<<<6144, 256, 0, stream>>>(Wqkv, WqkvB, 1572864);
  cvt_f32_bf16<<<4096, 256, 0, stream>>>(Wo,   WoB,   1048576);
  gemm_bt<0><<<dim3(24, 32), 256, 0, stream>>>(hsB, WqkvB, (void*)qkvB, 3072, 2048);
  rope_kernel<<<2560, 256, 0, stream>>>(qkvB, cosT, sinT, phs, Qb, Kb);
  vtrans<<<512, 256, 0, stream>>>(qkvB, VTb);
  attn_kernel<<<1024, 256, 0, stream>>>(Qb, Kb, VTb, Ao);
  gemm_bt<1><<<dim3(16, 32), 256, 0, stream>>>(Ao, WoB, (void*)out, 2048, 2048);
}

// Round 5
// 255.616 us; speedup vs baseline: 1.6568x; 1.1191x over previous
//
#include <hip/hip_runtime.h>
#include <stdint.h>

typedef unsigned short u16;
typedef short short8 __attribute__((ext_vector_type(8)));
typedef float f32x4 __attribute__((ext_vector_type(4)));
typedef uint32_t u32x4 __attribute__((ext_vector_type(4)));

#define S_LEN 2048
#define NQH 32
#define NKH 8
#define DHD 64

__device__ __forceinline__ float b2f(u16 u){
  union { uint32_t i; float f; } c; c.i = ((uint32_t)u) << 16; return c.f;
}
__device__ __forceinline__ u16 f2b(float f){
  union { float f; uint32_t i; } c; c.f = f;
  uint32_t r = c.i + 0x7fffu + ((c.i >> 16) & 1u);
  return (u16)(r >> 16);
}
__device__ __forceinline__ void gload_lds16(const void* g, void* l){
  __builtin_amdgcn_global_load_lds((const __attribute__((address_space(1))) uint32_t*)g,
                                   (__attribute__((address_space(3))) uint32_t*)l, 16, 0, 0);
}

// ---------------- fused fp32 -> bf16 convert (hs | Wqkv | Wo) ----------------
__global__ __launch_bounds__(256) void cvt_all(const float* __restrict__ hs,
                                               const float* __restrict__ wq,
                                               const float* __restrict__ wo,
                                               u16* __restrict__ hsB,
                                               u16* __restrict__ wqB,
                                               u16* __restrict__ woB){
  int i = blockIdx.x * 256 + threadIdx.x;       // 4718592 float4 total
  const float* src; u16* dst; int off;
  if (i < 2097152)      { src = hs; dst = hsB; off = i; }
  else if (i < 3670016) { src = wq; dst = wqB; off = i - 2097152; }
  else                  { src = wo; dst = woB; off = i - 3670016; }
  float4 v = ((const float4*)src)[off];
  uint2 o;
  o.x = (uint32_t)f2b(v.x) | ((uint32_t)f2b(v.y) << 16);
  o.y = (uint32_t)f2b(v.z) | ((uint32_t)f2b(v.w) << 16);
  ((uint2*)dst)[off] = o;
}

// ---------------- bf16 GEMM: C[M][N] = A[M][K] * B[N][K]^T ----------------
template<int OUT_F32>
__global__ __launch_bounds__(256)
void gemm_bt(const u16* __restrict__ A, const u16* __restrict__ Bm,
             void* __restrict__ Cp, int N, int K)
{
  __shared__ alignas(16) u16 lA[128 * 64];
  __shared__ alignas(16) u16 lB[128 * 64];
  const int tid = threadIdx.x;
  const int w = tid >> 6, l = tid & 63;
  const int lg = l >> 4, lc = l & 15;
  const int wm = w >> 1, wn = w & 1;
  const int m0 = blockIdx.y * 128, n0 = blockIdx.x * 128;
  const int srow = l >> 3, sc = l & 7;
  const size_t ldb = (size_t)K * 2;   // row bytes
  f32x4 acc[4][4] = {};
  const int kiters = K >> 6;
  for (int kt = 0; kt < kiters; ++kt){
    __syncthreads();
#pragma unroll
    for (int i = 0; i < 4; ++i){
      const int row = (i * 4 + w) * 8 + srow;
      const int gc = ((sc ^ (row & 7)) << 4);
      gload_lds16((const char*)A + (size_t)(m0 + row) * ldb + (size_t)kt * 128 + gc,
                  (char*)lA + row * 128 + sc * 16);
    }
#pragma unroll
    for (int i = 0; i < 4; ++i){
      const int row = (i * 4 + w) * 8 + srow;
      const int gc = ((sc ^ (row & 7)) << 4);
      gload_lds16((const char*)Bm + (size_t)(n0 + row) * ldb + (size_t)kt * 128 + gc,
                  (char*)lB + row * 128 + sc * 16);
    }
    __syncthreads();
#pragma unroll
    for (int kk = 0; kk < 2; ++kk){
      short8 af[4], bfr[4];
#pragma unroll
      for (int mi = 0; mi < 4; ++mi){
        const int row = wm * 64 + mi * 16 + lc;
        const int cc = (kk * 4 + lg) ^ (row & 7);
        af[mi] = *(const short8*)((const char*)lA + row * 128 + cc * 16);
      }
#pragma unroll
      for (int ni = 0; ni < 4; ++ni){
        const int row = wn * 64 + ni * 16 + lc;
        const int cc = (kk * 4 + lg) ^ (row & 7);
        bfr[ni] = *(const short8*)((const char*)lB + row * 128 + cc * 16);
      }
#pragma unroll
      for (int mi = 0; mi < 4; ++mi)
#pragma unroll
        for (int ni = 0; ni < 4; ++ni)
          acc[mi][ni] = __builtin_amdgcn_mfma_f32_16x16x32_bf16(af[mi], bfr[ni], acc[mi][ni], 0, 0, 0);
    }
  }
  const int r0 = m0 + wm * 64 + lg * 4;
  const int c0 = n0 + wn * 64 + lc;
#pragma unroll
  for (int mi = 0; mi < 4; ++mi)
#pragma unroll
    for (int ni = 0; ni < 4; ++ni)
#pragma unroll
      for (int j = 0; j < 4; ++j){
        const size_t idx = (size_t)(r0 + mi * 16 + j) * (size_t)N + (size_t)(c0 + ni * 16);
        if (OUT_F32) ((float*)Cp)[idx] = acc[mi][ni][j];
        else         ((u16*)Cp)[idx]  = f2b(acc[mi][ni][j]);
      }
}

// ---------------- RoPE + scales; qkv[b][s][48][64] -> Q[b][h][s][64], K[b][kh][s][64] ----------------
__global__ __launch_bounds__(256)
void rope_kernel(const u16* __restrict__ qkv, const float* __restrict__ cosT,
                 const float* __restrict__ sinT, const float* __restrict__ phs,
                 u16* __restrict__ Qo, u16* __restrict__ Ko)
{
  int id = blockIdx.x * 256 + threadIdx.x;      // B*40*S*4 = 655360
  int b = (id >= 327680) ? 1 : 0;
  int rem = id - b * 327680;
  int head = rem >> 13;                         // 0..39
  int s = (rem >> 2) & 2047;
  int d0 = (rem & 3) << 4;                      // 0,16,32,48
  const u16* src = qkv + (((size_t)(b * S_LEN + s) * 48 + head) << 6);
  uint4 xa = *(const uint4*)(src + d0);
  uint4 xb = *(const uint4*)(src + d0 + 8);
  int d0p = (d0 + 32) & 63;
  uint4 pa = *(const uint4*)(src + d0p);
  uint4 pb = *(const uint4*)(src + d0p + 8);
  const float* cp = cosT + s * 64 + d0;
  const float* sp = sinT + s * 64 + d0;
  const float sgn = (d0 < 32) ? -1.f : 1.f;
  const float scale = 1.2f * (head < NQH ? phs[b * NQH + head] : 1.f);
  uint32_t xs[4] = {xa.x, xa.y, xa.z, xa.w};
  uint32_t xs2[4] = {xb.x, xb.y, xb.z, xb.w};
  uint32_t ps[4] = {pa.x, pa.y, pa.z, pa.w};
  uint32_t ps2[4] = {pb.x, pb.y, pb.z, pb.w};
  uint32_t ow[8];
#pragma unroll
  for (int k = 0; k < 4; ++k){
    float v0 = b2f((u16)(xs[k] & 0xffff)) * cp[2*k]   + sgn * b2f((u16)(ps[k] & 0xffff)) * sp[2*k];
    float v1 = b2f((u16)(xs[k] >> 16))    * cp[2*k+1] + sgn * b2f((u16)(ps[k] >> 16))    * sp[2*k+1];
    ow[k] = (uint32_t)f2b(v0 * scale) | ((uint32_t)f2b(v1 * scale) << 16);
  }
#pragma unroll
  for (int k = 0; k < 4; ++k){
    float v0 = b2f((u16)(xs2[k] & 0xffff)) * cp[8+2*k]   + sgn * b2f((u16)(ps2[k] & 0xffff)) * sp[8+2*k];
    float v1 = b2f((u16)(xs2[k] >> 16))    * cp[8+2*k+1] + sgn * b2f((u16)(ps2[k] >> 16))    * sp[8+2*k+1];
    ow[4+k] = (uint32_t)f2b(v0 * scale) | ((uint32_t)f2b(v1 * scale) << 16);
  }
  u16* dst;
  if (head < NQH) dst = Qo + (((size_t)(b * NQH + head) * S_LEN + s) << 6) + d0;
  else            dst = Ko + (((size_t)(b * NKH + head - NQH) * S_LEN + s) << 6) + d0;
  uint4 o0 = {ow[0], ow[1], ow[2], ow[3]};
  uint4 o1 = {ow[4], ow[5], ow[6], ow[7]};
  *(uint4*)dst = o0;
  *(uint4*)(dst + 8) = o1;
}

// ---------------- V transpose: qkv v-heads -> VT[b][kh][d][s] ----------------
__global__ __launch_bounds__(256)
void vtrans(const u16* __restrict__ qkv, u16* __restrict__ VT)
{
  int bid = blockIdx.x;                 // (b*8+kh)*32 + st
  int st = bid & 31, kh = (bid >> 5) & 7, b = bid >> 8;
  __shared__ alignas(16) u16 t[64][72];
  int tid = threadIdx.x;
  int r = tid >> 2, c4 = tid & 3;
  const u16* src = qkv + (((size_t)(b * S_LEN + st * 64 + r) * 48 + 40 + kh) << 6) + c4 * 16;
  *(uint4*)&t[r][c4 * 16]     = *(const uint4*)src;
  *(uint4*)&t[r][c4 * 16 + 8] = *(const uint4*)(src + 8);
  __syncthreads();
  u16 o[16];
#pragma unroll
  for (int i = 0; i < 16; ++i) o[i] = t[c4 * 16 + i][r];   // r = d row now
  u16* dst = VT + ((size_t)(b * NKH + kh) * 64 + r) * S_LEN + st * 64 + c4 * 16;
  uint4 o0 = { (uint32_t)o[0] | ((uint32_t)o[1] << 16),  (uint32_t)o[2] | ((uint32_t)o[3] << 16),
               (uint32_t)o[4] | ((uint32_t)o[5] << 16),  (uint32_t)o[6] | ((uint32_t)o[7] << 16) };
  uint4 o1 = { (uint32_t)o[8] | ((uint32_t)o[9] << 16),  (uint32_t)o[10] | ((uint32_t)o[11] << 16),
               (uint32_t)o[12] | ((uint32_t)o[13] << 16),(uint32_t)o[14] | ((uint32_t)o[15] << 16) };
  *(uint4*)dst = o0;
  *(uint4*)(dst + 8) = o1;
}

// ---------------- causal GQA flash attention ----------------
// Complement-paired (qt0=p, qt1=31-p; 33 tile-units/block).
// Swapped QK^T (S^T = mfma(K,Q)): lane owns q-row q=lc -> in-lane softmax,
// 2 shuffles per reduce. P redistributed to PV B-frag via shfl (no LDS):
// target needs word nj = kk2*2 + (lg_t>=2) -> publish BOTH nj words, select
// at target by lg&2 (R4 bug: selected with publisher's lg).
// PV = mfma(V^T, P^T) -> O^T. K/V double-buffered, counted vmcnt(4).
__global__ __launch_bounds__(256, 2)
void attn_kernel(const u16* __restrict__ Q, const u16* __restrict__ Kr,
                 const u16* __restrict__ VT, u16* __restrict__ Ao)
{
  int bid = blockIdx.x;
  int p  = bid & 15;
  int g  = (bid >> 4) & 3;
  int kh = (bid >> 6) & 7;
  int b  = bid >> 9;
  int h = kh * 4 + g;
  const int qt0 = p, qt1 = 31 - p;     // chunk tile indices (64-row units)

  __shared__ alignas(16) u16 lK[2][64 * 64];     // [buf][j][d], swizzled
  __shared__ alignas(16) u16 lV[2][64 * 64];     // [buf][d][j], swizzled

  const int tid = threadIdx.x;
  const int w = tid >> 6, l = tid & 63;
  const int lg = l >> 4, lc = l & 15;
  const int srow = l >> 3, sc = l & 7;

  const float kscale = 0.18033688011112042f;     // SM_SCALE * log2(e)

  // Q fragments (B-operand layout): q = qt*64 + w*16 + lc, d = kk*32 + lg*8
  short8 qf[2][2];
  {
    const u16* qbase = Q + ((size_t)(b * NQH + h) * S_LEN) * 64;
#pragma unroll
    for (int kk = 0; kk < 2; ++kk){
      qf[0][kk] = *(const short8*)(qbase + (size_t)(qt0 * 64 + w * 16 + lc) * 64 + kk * 32 + lg * 8);
      qf[1][kk] = *(const short8*)(qbase + (size_t)(qt1 * 64 + w * 16 + lc) * 64 + kk * 32 + lg * 8);
    }
  }

  const u16* Kb = Kr + (size_t)(b * NKH + kh) * S_LEN * 64;
  const u16* Vb = VT + (size_t)(b * NKH + kh) * 64 * S_LEN;

  f32x4 o[2][4] = {};                  // O^T frag: row d = dn*16+lg*4+jj, col q = lc
  float mrow[2] = {-3.0e38f, -3.0e38f};
  float lsum[2] = {0.f, 0.f};

  const int nt = qt1 + 1;

#define STAGE(T, BSEL) do { \
    _Pragma("unroll") \
    for (int i_ = 0; i_ < 2; ++i_){ \
      const int row_ = (i_ * 4 + w) * 8 + srow; \
      const int gc_ = ((sc ^ (row_ & 7)) << 4); \
      gload_lds16((const char*)(Kb + (size_t)((T) * 64 + row_) * 64) + gc_, \
                  (char*)lK[BSEL] + row_ * 128 + sc * 16); \
    } \
    _Pragma("unroll") \
    for (int i_ = 0; i_ < 2; ++i_){ \
      const int row_ = (i_ * 4 + w) * 8 + srow; \
      const int gc_ = ((sc ^ (row_ & 7)) << 4); \
      gload_lds16((const char*)(Vb + (size_t)row_ * S_LEN + (T) * 64) + gc_, \
                  (char*)lV[BSEL] + row_ * 128 + sc * 16); \
    } \
  } while (0)

  STAGE(0, 0);

  for (int t = 0; t < nt; ++t){
    const int cur = t & 1;
    const bool act0 = (t <= qt0);
    if (t + 1 < nt){
      STAGE(t + 1, cur ^ 1);
      asm volatile("s_waitcnt vmcnt(4)" ::: "memory");   // tile-t loads landed
    } else {
      asm volatile("s_waitcnt vmcnt(0)" ::: "memory");
    }
    __builtin_amdgcn_s_barrier();

    // S^T = K Q^T : sv[c][nj][jj] = S[q=lc][k = t*64 + nj*16 + lg*4 + jj]
    f32x4 sv[2][4] = {};
    __builtin_amdgcn_s_setprio(1);
#pragma unroll
    for (int kk = 0; kk < 2; ++kk){
      short8 kf[4];
#pragma unroll
      for (int nj = 0; nj < 4; ++nj){
        const int row = nj * 16 + lc;
        const int cc = (kk * 4 + lg) ^ (row & 7);
        kf[nj] = *(const short8*)((const char*)lK[cur] + row * 128 + cc * 16);
      }
      if (act0)
#pragma unroll
        for (int nj = 0; nj < 4; ++nj)
          sv[0][nj] = __builtin_amdgcn_mfma_f32_16x16x32_bf16(kf[nj], qf[0][kk], sv[0][nj], 0, 0, 0);
#pragma unroll
      for (int nj = 0; nj < 4; ++nj)
        sv[1][nj] = __builtin_amdgcn_mfma_f32_16x16x32_bf16(kf[nj], qf[1][kk], sv[1][nj], 0, 0, 0);
    }
    __builtin_amdgcn_s_setprio(0);

    // per-chunk in-lane online softmax + bf16 pack + shfl redistribution
    uint32_t pw[2][2][4];              // [chunk][kk2][word] -> PV B-frag
#pragma unroll
    for (int c = 0; c < 2; ++c){
      if (c == 0 && !act0) continue;
      const int qt = c ? qt1 : qt0;
      if (t == qt){                    // diagonal: mask k > q (raw domain)
        const int qoff = w * 16 + lc;
#pragma unroll
        for (int nj = 0; nj < 4; ++nj)
#pragma unroll
          for (int jj = 0; jj < 4; ++jj){
            const int koff = nj * 16 + lg * 4 + jj;
            if (koff > qoff) sv[c][nj][jj] = -3.0e38f;
          }
      }
      float mu = sv[c][0][0];
#pragma unroll
      for (int nj = 0; nj < 4; ++nj)
#pragma unroll
        for (int jj = 0; jj < 4; ++jj) mu = fmaxf(mu, sv[c][nj][jj]);
      mu = fmaxf(mu, __shfl_xor(mu, 16));
      mu = fmaxf(mu, __shfl_xor(mu, 32));
      const float mnew = fmaxf(mrow[c], mu * kscale);
      const float sf = __builtin_amdgcn_exp2f(mrow[c] - mnew);
      mrow[c] = mnew;
      float ps = 0.f;
#pragma unroll
      for (int nj = 0; nj < 4; ++nj)
#pragma unroll
        for (int jj = 0; jj < 4; ++jj){
          const float pv = __builtin_amdgcn_exp2f(sv[c][nj][jj] * kscale - mnew);
          sv[c][nj][jj] = pv;
          ps += pv;
        }
      ps += __shfl_xor(ps, 16);
      ps += __shfl_xor(ps, 32);
      lsum[c] = lsum[c] * sf + ps;
#pragma unroll
      for (int dn = 0; dn < 4; ++dn)
#pragma unroll
        for (int jj = 0; jj < 4; ++jj) o[c][dn][jj] *= sf;
      // pack p -> bf16 pairs; rx[nj] = (jj=0,1), ry[nj] = (jj=2,3)
      uint32_t rx[4], ry[4];
#pragma unroll
      for (int nj = 0; nj < 4; ++nj){
        rx[nj] = (uint32_t)f2b(sv[c][nj][0]) | ((uint32_t)f2b(sv[c][nj][1]) << 16);
        ry[nj] = (uint32_t)f2b(sv[c][nj][2]) | ((uint32_t)f2b(sv[c][nj][3]) << 16);
      }
      // redistribute: target (lg,lc) kk2 element e needs
      //   src lane (lg&1)*32 + (e>=4)*16 + lc, word rx/ry[kk2*2 + (lg>=2)]
      // nj depends on TARGET lg -> shuffle both nj words, select by lg&2.
      const int srcA = (lg & 1) * 32 + lc;
      const bool hi = (lg & 2) != 0;
#pragma unroll
      for (int kk2 = 0; kk2 < 2; ++kk2){
        uint32_t x0 = (uint32_t)__shfl((int)rx[kk2 * 2],     srcA);
        uint32_t x1 = (uint32_t)__shfl((int)rx[kk2 * 2 + 1], srcA);
        uint32_t y0 = (uint32_t)__shfl((int)ry[kk2 * 2],     srcA);
        uint32_t y1 = (uint32_t)__shfl((int)ry[kk2 * 2 + 1], srcA);
        pw[c][kk2][0] = hi ? x1 : x0;
        pw[c][kk2][1] = hi ? y1 : y0;
        x0 = (uint32_t)__shfl((int)rx[kk2 * 2],     srcA + 16);
        x1 = (uint32_t)__shfl((int)rx[kk2 * 2 + 1], srcA + 16);
        y0 = (uint32_t)__shfl((int)ry[kk2 * 2],     srcA + 16);
        y1 = (uint32_t)__shfl((int)ry[kk2 * 2 + 1], srcA + 16);
        pw[c][kk2][2] = hi ? x1 : x0;
        pw[c][kk2][3] = hi ? y1 : y0;
      }
    }

    // O^T += V^T P^T
    __builtin_amdgcn_s_setprio(1);
#pragma unroll
    for (int kk2 = 0; kk2 < 2; ++kk2){
      short8 vf[4];
#pragma unroll
      for (int dn = 0; dn < 4; ++dn){
        const int row = dn * 16 + lc;
        const int cc = (kk2 * 4 + lg) ^ (row & 7);
        vf[dn] = *(const short8*)((const char*)lV[cur] + row * 128 + cc * 16);
      }
#pragma unroll
      for (int c = 0; c < 2; ++c){
        if (c == 0 && !act0) continue;
        u32x4 pwv = { pw[c][kk2][0], pw[c][kk2][1], pw[c][kk2][2], pw[c][kk2][3] };
        const short8 pb = __builtin_bit_cast(short8, pwv);
#pragma unroll
        for (int dn = 0; dn < 4; ++dn)
          o[c][dn] = __builtin_amdgcn_mfma_f32_16x16x32_bf16(vf[dn], pb, o[c][dn], 0, 0, 0);
      }
    }
    __builtin_amdgcn_s_setprio(0);
    __builtin_amdgcn_s_barrier();
  }
#undef STAGE

  // epilogue: O^T frag -> Ao[b][s=q][h*64+d], 8B packed stores (4 d per lane)
#pragma unroll
  for (int c = 0; c < 2; ++c){
    const int qt = c ? qt1 : qt0;
    const float inv = 1.f / lsum[c];
    const int sq = qt * 64 + w * 16 + lc;
#pragma unroll
    for (int dn = 0; dn < 4; ++dn){
      uint2 pk;
      pk.x = (uint32_t)f2b(o[c][dn][0] * inv) | ((uint32_t)f2b(o[c][dn][1] * inv) << 16);
      pk.y = (uint32_t)f2b(o[c][dn][2] * inv) | ((uint32_t)f2b(o[c][dn][3] * inv) << 16);
      const int col = h * 64 + dn * 16 + lg * 4;
      *(uint2*)&Ao[(size_t)(b * S_LEN + sq) * 2048 + col] = pk;
    }
  }
}

// ---------------- launcher ----------------
extern "C" void kernel_launch(void* const* d_in, const int* in_sizes, int n_in,
                              void* d_out, int out_size, void* d_ws, size_t ws_size,
                              hipStream_t stream)
{
  const float* cosT = (const float*)d_in[0];
  const float* sinT = (const float*)d_in[1];
  const float* hs   = (const float*)d_in[2];
  const float* phs  = (const float*)d_in[3];
  const float* Wqkv = (const float*)d_in[4];
  const float* Wo   = (const float*)d_in[5];
  float* out = (float*)d_out;
  char* ws = (char*)d_ws;

  u16* hsB   = (u16*)(ws);               // 16,777,216 B (aliased as attn_out later)
  u16* WqkvB = (u16*)(ws + 16777216);    // 12,582,912 B
  u16* WoB   = (u16*)(ws + 29360128);    //  8,388,608 B
  u16* qkvB  = (u16*)(ws + 37748736);    // 25,165,824 B
  u16* Qb    = (u16*)(ws + 62914560);    // 16,777,216 B
  u16* Kb    = (u16*)(ws + 79691776);    //  4,194,304 B
  u16* VTb   = (u16*)(ws + 83886080);    //  4,194,304 B  (total 88,080,384 B)
  u16* Ao    = hsB;                      // hsB dead after GEMM1

  cvt_all<<<18432, 256, 0, stream>>>(hs, Wqkv, Wo, hsB, WqkvB, WoB);
  gemm_bt<0><<<dim3(24, 32), 256, 0, stream>>>(hsB, WqkvB, (void*)qkvB, 3072, 2048);
  rope_kernel<<<2560, 256, 0, stream>>>(qkvB, cosT, sinT, phs, Qb, Kb);
  vtrans<<<512, 256, 0, stream>>>(qkvB, VTb);
  attn_kernel<<<1024, 256, 0, stream>>>(Qb, Kb, VTb, Ao);
  gemm_bt<1><<<dim3(16, 32), 256, 0, stream>>>(Ao, WoB, (void*)out, 2048, 2048);
}

// Round 6
// 248.061 us; speedup vs baseline: 1.7072x; 1.0305x over previous
//
#include <hip/hip_runtime.h>
#include <stdint.h>

typedef unsigned short u16;
typedef short short8 __attribute__((ext_vector_type(8)));
typedef float f32x4 __attribute__((ext_vector_type(4)));
typedef uint32_t u32x4 __attribute__((ext_vector_type(4)));

#define S_LEN 2048
#define NQH 32
#define NKH 8
#define DHD 64

__device__ __forceinline__ float b2f(u16 u){
  union { uint32_t i; float f; } c; c.i = ((uint32_t)u) << 16; return c.f;
}
__device__ __forceinline__ u16 f2b(float f){
  union { float f; uint32_t i; } c; c.f = f;
  uint32_t r = c.i + 0x7fffu + ((c.i >> 16) & 1u);
  return (u16)(r >> 16);
}
__device__ __forceinline__ uint32_t cvt_pk_bf16(float lo, float hi){
  uint32_t r;
  asm("v_cvt_pk_bf16_f32 %0, %1, %2" : "=v"(r) : "v"(lo), "v"(hi));
  return r;
}
__device__ __forceinline__ void gload_lds16(const void* g, void* l){
  __builtin_amdgcn_global_load_lds((const __attribute__((address_space(1))) uint32_t*)g,
                                   (__attribute__((address_space(3))) uint32_t*)l, 16, 0, 0);
}

// ---------------- fused fp32 -> bf16 convert (hs | Wqkv | Wo) ----------------
__global__ __launch_bounds__(256) void cvt_all(const float* __restrict__ hs,
                                               const float* __restrict__ wq,
                                               const float* __restrict__ wo,
                                               u16* __restrict__ hsB,
                                               u16* __restrict__ wqB,
                                               u16* __restrict__ woB){
  int i = blockIdx.x * 256 + threadIdx.x;       // 4718592 float4 total
  const float* src; u16* dst; int off;
  if (i < 2097152)      { src = hs; dst = hsB; off = i; }
  else if (i < 3670016) { src = wq; dst = wqB; off = i - 2097152; }
  else                  { src = wo; dst = woB; off = i - 3670016; }
  float4 v = ((const float4*)src)[off];
  uint2 o;
  o.x = (uint32_t)f2b(v.x) | ((uint32_t)f2b(v.y) << 16);
  o.y = (uint32_t)f2b(v.z) | ((uint32_t)f2b(v.w) << 16);
  ((uint2*)dst)[off] = o;
}

// ---------------- bf16 GEMM: C[M][N] = A[M][K] * B[N][K]^T ----------------
template<int OUT_F32>
__global__ __launch_bounds__(256)
void gemm_bt(const u16* __restrict__ A, const u16* __restrict__ Bm,
             void* __restrict__ Cp, int N, int K)
{
  __shared__ alignas(16) u16 lA[128 * 64];
  __shared__ alignas(16) u16 lB[128 * 64];
  const int tid = threadIdx.x;
  const int w = tid >> 6, l = tid & 63;
  const int lg = l >> 4, lc = l & 15;
  const int wm = w >> 1, wn = w & 1;
  const int m0 = blockIdx.y * 128, n0 = blockIdx.x * 128;
  const int srow = l >> 3, sc = l & 7;
  const size_t ldb = (size_t)K * 2;   // row bytes
  f32x4 acc[4][4] = {};
  const int kiters = K >> 6;
  for (int kt = 0; kt < kiters; ++kt){
    __syncthreads();
#pragma unroll
    for (int i = 0; i < 4; ++i){
      const int row = (i * 4 + w) * 8 + srow;
      const int gc = ((sc ^ (row & 7)) << 4);
      gload_lds16((const char*)A + (size_t)(m0 + row) * ldb + (size_t)kt * 128 + gc,
                  (char*)lA + row * 128 + sc * 16);
    }
#pragma unroll
    for (int i = 0; i < 4; ++i){
      const int row = (i * 4 + w) * 8 + srow;
      const int gc = ((sc ^ (row & 7)) << 4);
      gload_lds16((const char*)Bm + (size_t)(n0 + row) * ldb + (size_t)kt * 128 + gc,
                  (char*)lB + row * 128 + sc * 16);
    }
    __syncthreads();
#pragma unroll
    for (int kk = 0; kk < 2; ++kk){
      short8 af[4], bfr[4];
#pragma unroll
      for (int mi = 0; mi < 4; ++mi){
        const int row = wm * 64 + mi * 16 + lc;
        const int cc = (kk * 4 + lg) ^ (row & 7);
        af[mi] = *(const short8*)((const char*)lA + row * 128 + cc * 16);
      }
#pragma unroll
      for (int ni = 0; ni < 4; ++ni){
        const int row = wn * 64 + ni * 16 + lc;
        const int cc = (kk * 4 + lg) ^ (row & 7);
        bfr[ni] = *(const short8*)((const char*)lB + row * 128 + cc * 16);
      }
#pragma unroll
      for (int mi = 0; mi < 4; ++mi)
#pragma unroll
        for (int ni = 0; ni < 4; ++ni)
          acc[mi][ni] = __builtin_amdgcn_mfma_f32_16x16x32_bf16(af[mi], bfr[ni], acc[mi][ni], 0, 0, 0);
    }
  }
  const int r0 = m0 + wm * 64 + lg * 4;
  const int c0 = n0 + wn * 64 + lc;
#pragma unroll
  for (int mi = 0; mi < 4; ++mi)
#pragma unroll
    for (int ni = 0; ni < 4; ++ni)
#pragma unroll
      for (int j = 0; j < 4; ++j){
        const size_t idx = (size_t)(r0 + mi * 16 + j) * (size_t)N + (size_t)(c0 + ni * 16);
        if (OUT_F32) ((float*)Cp)[idx] = acc[mi][ni][j];
        else         ((u16*)Cp)[idx]  = f2b(acc[mi][ni][j]);
      }
}

// ---------------- RoPE + scales; qkv[b][s][48][64] -> Q[b][h][s][64], K[b][kh][s][64] ----------------
// Q additionally folded by SM_SCALE*log2(e) so attention scores exit QK^T in exp2 domain.
__global__ __launch_bounds__(256)
void rope_kernel(const u16* __restrict__ qkv, const float* __restrict__ cosT,
                 const float* __restrict__ sinT, const float* __restrict__ phs,
                 u16* __restrict__ Qo, u16* __restrict__ Ko)
{
  int id = blockIdx.x * 256 + threadIdx.x;      // B*40*S*4 = 655360
  int b = (id >= 327680) ? 1 : 0;
  int rem = id - b * 327680;
  int head = rem >> 13;                         // 0..39
  int s = (rem >> 2) & 2047;
  int d0 = (rem & 3) << 4;                      // 0,16,32,48
  const u16* src = qkv + (((size_t)(b * S_LEN + s) * 48 + head) << 6);
  uint4 xa = *(const uint4*)(src + d0);
  uint4 xb = *(const uint4*)(src + d0 + 8);
  int d0p = (d0 + 32) & 63;
  uint4 pa = *(const uint4*)(src + d0p);
  uint4 pb = *(const uint4*)(src + d0p + 8);
  const float* cp = cosT + s * 64 + d0;
  const float* sp = sinT + s * 64 + d0;
  const float sgn = (d0 < 32) ? -1.f : 1.f;
  const float kscale = 0.18033688011112042f;    // SM_SCALE * log2(e)
  const float scale = (head < NQH) ? 1.2f * kscale * phs[b * NQH + head] : 1.2f;
  uint32_t xs[4] = {xa.x, xa.y, xa.z, xa.w};
  uint32_t xs2[4] = {xb.x, xb.y, xb.z, xb.w};
  uint32_t ps[4] = {pa.x, pa.y, pa.z, pa.w};
  uint32_t ps2[4] = {pb.x, pb.y, pb.z, pb.w};
  uint32_t ow[8];
#pragma unroll
  for (int k = 0; k < 4; ++k){
    float v0 = b2f((u16)(xs[k] & 0xffff)) * cp[2*k]   + sgn * b2f((u16)(ps[k] & 0xffff)) * sp[2*k];
    float v1 = b2f((u16)(xs[k] >> 16))    * cp[2*k+1] + sgn * b2f((u16)(ps[k] >> 16))    * sp[2*k+1];
    ow[k] = (uint32_t)f2b(v0 * scale) | ((uint32_t)f2b(v1 * scale) << 16);
  }
#pragma unroll
  for (int k = 0; k < 4; ++k){
    float v0 = b2f((u16)(xs2[k] & 0xffff)) * cp[8+2*k]   + sgn * b2f((u16)(ps2[k] & 0xffff)) * sp[8+2*k];
    float v1 = b2f((u16)(xs2[k] >> 16))    * cp[8+2*k+1] + sgn * b2f((u16)(ps2[k] >> 16))    * sp[8+2*k+1];
    ow[4+k] = (uint32_t)f2b(v0 * scale) | ((uint32_t)f2b(v1 * scale) << 16);
  }
  u16* dst;
  if (head < NQH) dst = Qo + (((size_t)(b * NQH + head) * S_LEN + s) << 6) + d0;
  else            dst = Ko + (((size_t)(b * NKH + head - NQH) * S_LEN + s) << 6) + d0;
  uint4 o0 = {ow[0], ow[1], ow[2], ow[3]};
  uint4 o1 = {ow[4], ow[5], ow[6], ow[7]};
  *(uint4*)dst = o0;
  *(uint4*)(dst + 8) = o1;
}

// ---------------- V transpose: qkv v-heads -> VT[b][kh][d][s] ----------------
__global__ __launch_bounds__(256)
void vtrans(const u16* __restrict__ qkv, u16* __restrict__ VT)
{
  int bid = blockIdx.x;                 // (b*8+kh)*32 + st
  int st = bid & 31, kh = (bid >> 5) & 7, b = bid >> 8;
  __shared__ alignas(16) u16 t[64][72];
  int tid = threadIdx.x;
  int r = tid >> 2, c4 = tid & 3;
  const u16* src = qkv + (((size_t)(b * S_LEN + st * 64 + r) * 48 + 40 + kh) << 6) + c4 * 16;
  *(uint4*)&t[r][c4 * 16]     = *(const uint4*)src;
  *(uint4*)&t[r][c4 * 16 + 8] = *(const uint4*)(src + 8);
  __syncthreads();
  u16 o[16];
#pragma unroll
  for (int i = 0; i < 16; ++i) o[i] = t[c4 * 16 + i][r];   // r = d row now
  u16* dst = VT + ((size_t)(b * NKH + kh) * 64 + r) * S_LEN + st * 64 + c4 * 16;
  uint4 o0 = { (uint32_t)o[0] | ((uint32_t)o[1] << 16),  (uint32_t)o[2] | ((uint32_t)o[3] << 16),
               (uint32_t)o[4] | ((uint32_t)o[5] << 16),  (uint32_t)o[6] | ((uint32_t)o[7] << 16) };
  uint4 o1 = { (uint32_t)o[8] | ((uint32_t)o[9] << 16),  (uint32_t)o[10] | ((uint32_t)o[11] << 16),
               (uint32_t)o[12] | ((uint32_t)o[13] << 16),(uint32_t)o[14] | ((uint32_t)o[15] << 16) };
  *(uint4*)dst = o0;
  *(uint4*)(dst + 8) = o1;
}

// ---------------- causal GQA flash attention ----------------
// Complement-paired (qt0=p, qt1=31-p; 33 tile-units/block).
// Swapped QK^T (S^T = mfma(K,Q)) -> in-lane softmax (scores pre-scaled to
// exp2 domain in RoPE). Defer-max (THR=8*log2e): skip rescale unless a new
// max exceeds threshold. P packed via v_cvt_pk_bf16_f32, redistributed to
// PV B-frag via shfl (publish both nj words, select by target lg&2).
// PV = mfma(V^T, P^T) -> O^T. K/V double-buffered, counted vmcnt(4).
__global__ __launch_bounds__(256, 2)
void attn_kernel(const u16* __restrict__ Q, const u16* __restrict__ Kr,
                 const u16* __restrict__ VT, u16* __restrict__ Ao)
{
  int bid = blockIdx.x;
  int p  = bid & 15;
  int g  = (bid >> 4) & 3;
  int kh = (bid >> 6) & 7;
  int b  = bid >> 9;
  int h = kh * 4 + g;
  const int qt0 = p, qt1 = 31 - p;     // chunk tile indices (64-row units)

  __shared__ alignas(16) u16 lK[2][64 * 64];     // [buf][j][d], swizzled
  __shared__ alignas(16) u16 lV[2][64 * 64];     // [buf][d][j], swizzled

  const int tid = threadIdx.x;
  const int w = tid >> 6, l = tid & 63;
  const int lg = l >> 4, lc = l & 15;
  const int srow = l >> 3, sc = l & 7;

  // Q fragments (B-operand layout): q = qt*64 + w*16 + lc, d = kk*32 + lg*8
  short8 qf[2][2];
  {
    const u16* qbase = Q + ((size_t)(b * NQH + h) * S_LEN) * 64;
#pragma unroll
    for (int kk = 0; kk < 2; ++kk){
      qf[0][kk] = *(const short8*)(qbase + (size_t)(qt0 * 64 + w * 16 + lc) * 64 + kk * 32 + lg * 8);
      qf[1][kk] = *(const short8*)(qbase + (size_t)(qt1 * 64 + w * 16 + lc) * 64 + kk * 32 + lg * 8);
    }
  }

  const u16* Kb = Kr + (size_t)(b * NKH + kh) * S_LEN * 64;
  const u16* Vb = VT + (size_t)(b * NKH + kh) * 64 * S_LEN;

  f32x4 o[2][4] = {};                  // O^T frag: row d = dn*16+lg*4+jj, col q = lc
  float mrow[2] = {-3.0e38f, -3.0e38f};
  float lsum[2] = {0.f, 0.f};

  const int nt = qt1 + 1;

#define STAGE(T, BSEL) do { \
    _Pragma("unroll") \
    for (int i_ = 0; i_ < 2; ++i_){ \
      const int row_ = (i_ * 4 + w) * 8 + srow; \
      const int gc_ = ((sc ^ (row_ & 7)) << 4); \
      gload_lds16((const char*)(Kb + (size_t)((T) * 64 + row_) * 64) + gc_, \
                  (char*)lK[BSEL] + row_ * 128 + sc * 16); \
    } \
    _Pragma("unroll") \
    for (int i_ = 0; i_ < 2; ++i_){ \
      const int row_ = (i_ * 4 + w) * 8 + srow; \
      const int gc_ = ((sc ^ (row_ & 7)) << 4); \
      gload_lds16((const char*)(Vb + (size_t)row_ * S_LEN + (T) * 64) + gc_, \
                  (char*)lV[BSEL] + row_ * 128 + sc * 16); \
    } \
  } while (0)

  STAGE(0, 0);

  for (int t = 0; t < nt; ++t){
    const int cur = t & 1;
    const bool act0 = (t <= qt0);
    if (t + 1 < nt){
      STAGE(t + 1, cur ^ 1);
      asm volatile("s_waitcnt vmcnt(4)" ::: "memory");   // tile-t loads landed
    } else {
      asm volatile("s_waitcnt vmcnt(0)" ::: "memory");
    }
    __builtin_amdgcn_s_barrier();

    // S^T = K Q^T : sv[c][nj][jj] = S[q=lc][k = t*64 + nj*16 + lg*4 + jj]
    f32x4 sv[2][4] = {};
    __builtin_amdgcn_s_setprio(1);
#pragma unroll
    for (int kk = 0; kk < 2; ++kk){
      short8 kf[4];
#pragma unroll
      for (int nj = 0; nj < 4; ++nj){
        const int row = nj * 16 + lc;
        const int cc = (kk * 4 + lg) ^ (row & 7);
        kf[nj] = *(const short8*)((const char*)lK[cur] + row * 128 + cc * 16);
      }
      if (act0)
#pragma unroll
        for (int nj = 0; nj < 4; ++nj)
          sv[0][nj] = __builtin_amdgcn_mfma_f32_16x16x32_bf16(kf[nj], qf[0][kk], sv[0][nj], 0, 0, 0);
#pragma unroll
      for (int nj = 0; nj < 4; ++nj)
        sv[1][nj] = __builtin_amdgcn_mfma_f32_16x16x32_bf16(kf[nj], qf[1][kk], sv[1][nj], 0, 0, 0);
    }
    __builtin_amdgcn_s_setprio(0);

    // per-chunk in-lane online softmax (exp2 domain) + pk-pack + shfl redistribution
    uint32_t pw[2][2][4];              // [chunk][kk2][word] -> PV B-frag
#pragma unroll
    for (int c = 0; c < 2; ++c){
      if (c == 0 && !act0) continue;
      const int qt = c ? qt1 : qt0;
      if (t == qt){                    // diagonal: mask k > q
        const int qoff = w * 16 + lc;
#pragma unroll
        for (int nj = 0; nj < 4; ++nj)
#pragma unroll
          for (int jj = 0; jj < 4; ++jj){
            const int koff = nj * 16 + lg * 4 + jj;
            if (koff > qoff) sv[c][nj][jj] = -3.0e38f;
          }
      }
      float mu = sv[c][0][0];
#pragma unroll
      for (int nj = 0; nj < 4; ++nj)
#pragma unroll
        for (int jj = 0; jj < 4; ++jj) mu = fmaxf(mu, sv[c][nj][jj]);
      mu = fmaxf(mu, __shfl_xor(mu, 16));
      mu = fmaxf(mu, __shfl_xor(mu, 32));
      // defer-max: only rescale when max grew past THR (log2 domain)
      if (!__all(mu <= mrow[c] + 11.54f)){
        const float mnew = fmaxf(mrow[c], mu);
        const float sf = __builtin_amdgcn_exp2f(mrow[c] - mnew);
        mrow[c] = mnew;
        lsum[c] *= sf;
#pragma unroll
        for (int dn = 0; dn < 4; ++dn)
#pragma unroll
          for (int jj = 0; jj < 4; ++jj) o[c][dn][jj] *= sf;
      }
      const float mcur = mrow[c];
      float ps = 0.f;
#pragma unroll
      for (int nj = 0; nj < 4; ++nj)
#pragma unroll
        for (int jj = 0; jj < 4; ++jj){
          const float pv = __builtin_amdgcn_exp2f(sv[c][nj][jj] - mcur);
          sv[c][nj][jj] = pv;
          ps += pv;
        }
      ps += __shfl_xor(ps, 16);
      ps += __shfl_xor(ps, 32);
      lsum[c] += ps;
      // pack p -> bf16 pairs; rx[nj] = (jj=0,1), ry[nj] = (jj=2,3)
      uint32_t rx[4], ry[4];
#pragma unroll
      for (int nj = 0; nj < 4; ++nj){
        rx[nj] = cvt_pk_bf16(sv[c][nj][0], sv[c][nj][1]);
        ry[nj] = cvt_pk_bf16(sv[c][nj][2], sv[c][nj][3]);
      }
      // redistribute: target (lg,lc) kk2 element e needs
      //   src lane (lg&1)*32 + (e>=4)*16 + lc, word rx/ry[kk2*2 + (lg>=2)]
      const int srcA = (lg & 1) * 32 + lc;
      const bool hi = (lg & 2) != 0;
#pragma unroll
      for (int kk2 = 0; kk2 < 2; ++kk2){
        uint32_t x0 = (uint32_t)__shfl((int)rx[kk2 * 2],     srcA);
        uint32_t x1 = (uint32_t)__shfl((int)rx[kk2 * 2 + 1], srcA);
        uint32_t y0 = (uint32_t)__shfl((int)ry[kk2 * 2],     srcA);
        uint32_t y1 = (uint32_t)__shfl((int)ry[kk2 * 2 + 1], srcA);
        pw[c][kk2][0] = hi ? x1 : x0;
        pw[c][kk2][1] = hi ? y1 : y0;
        x0 = (uint32_t)__shfl((int)rx[kk2 * 2],     srcA + 16);
        x1 = (uint32_t)__shfl((int)rx[kk2 * 2 + 1], srcA + 16);
        y0 = (uint32_t)__shfl((int)ry[kk2 * 2],     srcA + 16);
        y1 = (uint32_t)__shfl((int)ry[kk2 * 2 + 1], srcA + 16);
        pw[c][kk2][2] = hi ? x1 : x0;
        pw[c][kk2][3] = hi ? y1 : y0;
      }
    }

    // O^T += V^T P^T
    __builtin_amdgcn_s_setprio(1);
#pragma unroll
    for (int kk2 = 0; kk2 < 2; ++kk2){
      short8 vf[4];
#pragma unroll
      for (int dn = 0; dn < 4; ++dn){
        const int row = dn * 16 + lc;
        const int cc = (kk2 * 4 + lg) ^ (row & 7);
        vf[dn] = *(const short8*)((const char*)lV[cur] + row * 128 + cc * 16);
      }
#pragma unroll
      for (int c = 0; c < 2; ++c){
        if (c == 0 && !act0) continue;
        u32x4 pwv = { pw[c][kk2][0], pw[c][kk2][1], pw[c][kk2][2], pw[c][kk2][3] };
        const short8 pb = __builtin_bit_cast(short8, pwv);
#pragma unroll
        for (int dn = 0; dn < 4; ++dn)
          o[c][dn] = __builtin_amdgcn_mfma_f32_16x16x32_bf16(vf[dn], pb, o[c][dn], 0, 0, 0);
      }
    }
    __builtin_amdgcn_s_setprio(0);
    __builtin_amdgcn_s_barrier();
  }
#undef STAGE

  // epilogue: O^T frag -> Ao[b][s=q][h*64+d], 8B packed stores (4 d per lane)
#pragma unroll
  for (int c = 0; c < 2; ++c){
    const int qt = c ? qt1 : qt0;
    const float inv = 1.f / lsum[c];
    const int sq = qt * 64 + w * 16 + lc;
#pragma unroll
    for (int dn = 0; dn < 4; ++dn){
      uint2 pk;
      pk.x = cvt_pk_bf16(o[c][dn][0] * inv, o[c][dn][1] * inv);
      pk.y = cvt_pk_bf16(o[c][dn][2] * inv, o[c][dn][3] * inv);
      const int col = h * 64 + dn * 16 + lg * 4;
      *(uint2*)&Ao[(size_t)(b * S_LEN + sq) * 2048 + col] = pk;
    }
  }
}

// ---------------- launcher ----------------
extern "C" void kernel_launch(void* const* d_in, const int* in_sizes, int n_in,
                              void* d_out, int out_size, void* d_ws, size_t ws_size,
                              hipStream_t stream)
{
  const float* cosT = (const float*)d_in[0];
  const float* sinT = (const float*)d_in[1];
  const float* hs   = (const float*)d_in[2];
  const float* phs  = (const float*)d_in[3];
  const float* Wqkv = (const float*)d_in[4];
  const float* Wo   = (const float*)d_in[5];
  float* out = (float*)d_out;
  char* ws = (char*)d_ws;

  u16* hsB   = (u16*)(ws);               // 16,777,216 B (aliased as attn_out later)
  u16* WqkvB = (u16*)(ws + 16777216);    // 12,582,912 B
  u16* WoB   = (u16*)(ws + 29360128);    //  8,388,608 B
  u16* qkvB  = (u16*)(ws + 37748736);    // 25,165,824 B
  u16* Qb    = (u16*)(ws + 62914560);    // 16,777,216 B
  u16* Kb    = (u16*)(ws + 79691776);    //  4,194,304 B
  u16* VTb   = (u16*)(ws + 83886080);    //  4,194,304 B  (total 88,080,384 B)
  u16* Ao    = hsB;                      // hsB dead after GEMM1

  cvt_all<<<18432, 256, 0, stream>>>(hs, Wqkv, Wo, hsB, WqkvB, WoB);
  gemm_bt<0><<<dim3(24, 32), 256, 0, stream>>>(hsB, WqkvB, (void*)qkvB, 3072, 2048);
  rope_kernel<<<2560, 256, 0, stream>>>(qkvB, cosT, sinT, phs, Qb, Kb);
  vtrans<<<512, 256, 0, stream>>>(qkvB, VTb);
  attn_kernel<<<1024, 256, 0, stream>>>(Qb, Kb, VTb, Ao);
  gemm_bt<1><<<dim3(16, 32), 256, 0, stream>>>(Ao, WoB, (void*)out, 2048, 2048);
}

// Round 7
// 236.186 us; speedup vs baseline: 1.7931x; 1.0503x over previous
//
#include <hip/hip_runtime.h>
#include <stdint.h>

typedef unsigned short u16;
typedef short short8 __attribute__((ext_vector_type(8)));
typedef float f32x4 __attribute__((ext_vector_type(4)));
typedef uint32_t u32x4 __attribute__((ext_vector_type(4)));

#define S_LEN 2048
#define NQH 32
#define NKH 8
#define DHD 64

__device__ __forceinline__ float b2f(u16 u){
  union { uint32_t i; float f; } c; c.i = ((uint32_t)u) << 16; return c.f;
}
__device__ __forceinline__ u16 f2b(float f){
  union { float f; uint32_t i; } c; c.f = f;
  uint32_t r = c.i + 0x7fffu + ((c.i >> 16) & 1u);
  return (u16)(r >> 16);
}
__device__ __forceinline__ uint32_t cvt_pk_bf16(float lo, float hi){
  uint32_t r;
  asm("v_cvt_pk_bf16_f32 %0, %1, %2" : "=v"(r) : "v"(lo), "v"(hi));
  return r;
}
__device__ __forceinline__ void gload_lds16(const void* g, void* l){
  __builtin_amdgcn_global_load_lds((const __attribute__((address_space(1))) uint32_t*)g,
                                   (__attribute__((address_space(3))) uint32_t*)l, 16, 0, 0);
}

// ---------------- fused fp32 -> bf16 convert (hs | Wqkv | Wo) ----------------
__global__ __launch_bounds__(256) void cvt_all(const float* __restrict__ hs,
                                               const float* __restrict__ wq,
                                               const float* __restrict__ wo,
                                               u16* __restrict__ hsB,
                                               u16* __restrict__ wqB,
                                               u16* __restrict__ woB){
  int i = blockIdx.x * 256 + threadIdx.x;       // 4718592 float4 total
  const float* src; u16* dst; int off;
  if (i < 2097152)      { src = hs; dst = hsB; off = i; }
  else if (i < 3670016) { src = wq; dst = wqB; off = i - 2097152; }
  else                  { src = wo; dst = woB; off = i - 3670016; }
  float4 v = ((const float4*)src)[off];
  uint2 o;
  o.x = (uint32_t)f2b(v.x) | ((uint32_t)f2b(v.y) << 16);
  o.y = (uint32_t)f2b(v.z) | ((uint32_t)f2b(v.w) << 16);
  ((uint2*)dst)[off] = o;
}

// ---------------- bf16 GEMM: C[M][N] = A[M][K] * B[N][K]^T ----------------
template<int OUT_F32>
__global__ __launch_bounds__(256)
void gemm_bt(const u16* __restrict__ A, const u16* __restrict__ Bm,
             void* __restrict__ Cp, int N, int K)
{
  __shared__ alignas(16) u16 lA[128 * 64];
  __shared__ alignas(16) u16 lB[128 * 64];
  const int tid = threadIdx.x;
  const int w = tid >> 6, l = tid & 63;
  const int lg = l >> 4, lc = l & 15;
  const int wm = w >> 1, wn = w & 1;
  const int m0 = blockIdx.y * 128, n0 = blockIdx.x * 128;
  const int srow = l >> 3, sc = l & 7;
  const size_t ldb = (size_t)K * 2;   // row bytes
  f32x4 acc[4][4] = {};
  const int kiters = K >> 6;
  for (int kt = 0; kt < kiters; ++kt){
    __syncthreads();
#pragma unroll
    for (int i = 0; i < 4; ++i){
      const int row = (i * 4 + w) * 8 + srow;
      const int gc = ((sc ^ (row & 7)) << 4);
      gload_lds16((const char*)A + (size_t)(m0 + row) * ldb + (size_t)kt * 128 + gc,
                  (char*)lA + row * 128 + sc * 16);
    }
#pragma unroll
    for (int i = 0; i < 4; ++i){
      const int row = (i * 4 + w) * 8 + srow;
      const int gc = ((sc ^ (row & 7)) << 4);
      gload_lds16((const char*)Bm + (size_t)(n0 + row) * ldb + (size_t)kt * 128 + gc,
                  (char*)lB + row * 128 + sc * 16);
    }
    __syncthreads();
#pragma unroll
    for (int kk = 0; kk < 2; ++kk){
      short8 af[4], bfr[4];
#pragma unroll
      for (int mi = 0; mi < 4; ++mi){
        const int row = wm * 64 + mi * 16 + lc;
        const int cc = (kk * 4 + lg) ^ (row & 7);
        af[mi] = *(const short8*)((const char*)lA + row * 128 + cc * 16);
      }
#pragma unroll
      for (int ni = 0; ni < 4; ++ni){
        const int row = wn * 64 + ni * 16 + lc;
        const int cc = (kk * 4 + lg) ^ (row & 7);
        bfr[ni] = *(const short8*)((const char*)lB + row * 128 + cc * 16);
      }
#pragma unroll
      for (int mi = 0; mi < 4; ++mi)
#pragma unroll
        for (int ni = 0; ni < 4; ++ni)
          acc[mi][ni] = __builtin_amdgcn_mfma_f32_16x16x32_bf16(af[mi], bfr[ni], acc[mi][ni], 0, 0, 0);
    }
  }
  const int r0 = m0 + wm * 64 + lg * 4;
  const int c0 = n0 + wn * 64 + lc;
#pragma unroll
  for (int mi = 0; mi < 4; ++mi)
#pragma unroll
    for (int ni = 0; ni < 4; ++ni)
#pragma unroll
      for (int j = 0; j < 4; ++j){
        const size_t idx = (size_t)(r0 + mi * 16 + j) * (size_t)N + (size_t)(c0 + ni * 16);
        if (OUT_F32) ((float*)Cp)[idx] = acc[mi][ni][j];
        else         ((u16*)Cp)[idx]  = f2b(acc[mi][ni][j]);
      }
}

// ---------------- RoPE + scales; qkv[b][s][48][64] -> Q[b][h][s][64], K[b][kh][s][64] ----------------
// Q additionally folded by SM_SCALE*log2(e) so attention scores exit QK^T in exp2 domain.
__global__ __launch_bounds__(256)
void rope_kernel(const u16* __restrict__ qkv, const float* __restrict__ cosT,
                 const float* __restrict__ sinT, const float* __restrict__ phs,
                 u16* __restrict__ Qo, u16* __restrict__ Ko)
{
  int id = blockIdx.x * 256 + threadIdx.x;      // B*40*S*4 = 655360
  int b = (id >= 327680) ? 1 : 0;
  int rem = id - b * 327680;
  int head = rem >> 13;                         // 0..39
  int s = (rem >> 2) & 2047;
  int d0 = (rem & 3) << 4;                      // 0,16,32,48
  const u16* src = qkv + (((size_t)(b * S_LEN + s) * 48 + head) << 6);
  uint4 xa = *(const uint4*)(src + d0);
  uint4 xb = *(const uint4*)(src + d0 + 8);
  int d0p = (d0 + 32) & 63;
  uint4 pa = *(const uint4*)(src + d0p);
  uint4 pb = *(const uint4*)(src + d0p + 8);
  const float* cp = cosT + s * 64 + d0;
  const float* sp = sinT + s * 64 + d0;
  const float sgn = (d0 < 32) ? -1.f : 1.f;
  const float kscale = 0.18033688011112042f;    // SM_SCALE * log2(e)
  const float scale = (head < NQH) ? 1.2f * kscale * phs[b * NQH + head] : 1.2f;
  uint32_t xs[4] = {xa.x, xa.y, xa.z, xa.w};
  uint32_t xs2[4] = {xb.x, xb.y, xb.z, xb.w};
  uint32_t ps[4] = {pa.x, pa.y, pa.z, pa.w};
  uint32_t ps2[4] = {pb.x, pb.y, pb.z, pb.w};
  uint32_t ow[8];
#pragma unroll
  for (int k = 0; k < 4; ++k){
    float v0 = b2f((u16)(xs[k] & 0xffff)) * cp[2*k]   + sgn * b2f((u16)(ps[k] & 0xffff)) * sp[2*k];
    float v1 = b2f((u16)(xs[k] >> 16))    * cp[2*k+1] + sgn * b2f((u16)(ps[k] >> 16))    * sp[2*k+1];
    ow[k] = (uint32_t)f2b(v0 * scale) | ((uint32_t)f2b(v1 * scale) << 16);
  }
#pragma unroll
  for (int k = 0; k < 4; ++k){
    float v0 = b2f((u16)(xs2[k] & 0xffff)) * cp[8+2*k]   + sgn * b2f((u16)(ps2[k] & 0xffff)) * sp[8+2*k];
    float v1 = b2f((u16)(xs2[k] >> 16))    * cp[8+2*k+1] + sgn * b2f((u16)(ps2[k] >> 16))    * sp[8+2*k+1];
    ow[4+k] = (uint32_t)f2b(v0 * scale) | ((uint32_t)f2b(v1 * scale) << 16);
  }
  u16* dst;
  if (head < NQH) dst = Qo + (((size_t)(b * NQH + head) * S_LEN + s) << 6) + d0;
  else            dst = Ko + (((size_t)(b * NKH + head - NQH) * S_LEN + s) << 6) + d0;
  uint4 o0 = {ow[0], ow[1], ow[2], ow[3]};
  uint4 o1 = {ow[4], ow[5], ow[6], ow[7]};
  *(uint4*)dst = o0;
  *(uint4*)(dst + 8) = o1;
}

// ---------------- V transpose: qkv v-heads -> VT[b][kh][d][s] ----------------
__global__ __launch_bounds__(256)
void vtrans(const u16* __restrict__ qkv, u16* __restrict__ VT)
{
  int bid = blockIdx.x;                 // (b*8+kh)*32 + st
  int st = bid & 31, kh = (bid >> 5) & 7, b = bid >> 8;
  __shared__ alignas(16) u16 t[64][72];
  int tid = threadIdx.x;
  int r = tid >> 2, c4 = tid & 3;
  const u16* src = qkv + (((size_t)(b * S_LEN + st * 64 + r) * 48 + 40 + kh) << 6) + c4 * 16;
  *(uint4*)&t[r][c4 * 16]     = *(const uint4*)src;
  *(uint4*)&t[r][c4 * 16 + 8] = *(const uint4*)(src + 8);
  __syncthreads();
  u16 o[16];
#pragma unroll
  for (int i = 0; i < 16; ++i) o[i] = t[c4 * 16 + i][r];   // r = d row now
  u16* dst = VT + ((size_t)(b * NKH + kh) * 64 + r) * S_LEN + st * 64 + c4 * 16;
  uint4 o0 = { (uint32_t)o[0] | ((uint32_t)o[1] << 16),  (uint32_t)o[2] | ((uint32_t)o[3] << 16),
               (uint32_t)o[4] | ((uint32_t)o[5] << 16),  (uint32_t)o[6] | ((uint32_t)o[7] << 16) };
  uint4 o1 = { (uint32_t)o[8] | ((uint32_t)o[9] << 16),  (uint32_t)o[10] | ((uint32_t)o[11] << 16),
               (uint32_t)o[12] | ((uint32_t)o[13] << 16),(uint32_t)o[14] | ((uint32_t)o[15] << 16) };
  *(uint4*)dst = o0;
  *(uint4*)(dst + 8) = o1;
}

// ---------------- causal GQA flash attention ----------------
// Complement-paired (qt0=p, qt1=31-p in 64-row units; 17 BKV=128 units/block).
// BKV=128 double-buffered (64KB LDS): per-iteration compute (~2x) now covers
// staging latency, halves barrier count (R6 stall diagnosis). Swapped QK^T,
// in-lane softmax (exp2 domain from RoPE), defer-max, cvt_pk pack, shfl
// redistribution; lsum kept as per-lane partial, reduced once in epilogue.
__global__ __launch_bounds__(256, 2)
void attn_kernel(const u16* __restrict__ Q, const u16* __restrict__ Kr,
                 const u16* __restrict__ VT, u16* __restrict__ Ao)
{
  int bid = blockIdx.x;
  int p  = bid & 15;
  int g  = (bid >> 4) & 3;
  int kh = (bid >> 6) & 7;
  int b  = bid >> 9;
  int h = kh * 4 + g;
  const int qt0 = p, qt1 = 31 - p;     // chunk tile indices (64-row units)

  __shared__ alignas(16) u16 lK[2][128 * 64];    // [buf][kv j][d], swizzle ^(row&7)
  __shared__ alignas(16) u16 lV[2][64 * 128];    // [buf][d][kv j], swizzle ^(row&15)

  const int tid = threadIdx.x;
  const int w = tid >> 6, l = tid & 63;
  const int lg = l >> 4, lc = l & 15;

  // Q fragments (B-operand layout): q = qt*64 + w*16 + lc, d = kk*32 + lg*8
  short8 qf[2][2];
  {
    const u16* qbase = Q + ((size_t)(b * NQH + h) * S_LEN) * 64;
#pragma unroll
    for (int kk = 0; kk < 2; ++kk){
      qf[0][kk] = *(const short8*)(qbase + (size_t)(qt0 * 64 + w * 16 + lc) * 64 + kk * 32 + lg * 8);
      qf[1][kk] = *(const short8*)(qbase + (size_t)(qt1 * 64 + w * 16 + lc) * 64 + kk * 32 + lg * 8);
    }
  }

  const u16* Kb = Kr + (size_t)(b * NKH + kh) * S_LEN * 64;
  const u16* Vb = VT + (size_t)(b * NKH + kh) * 64 * S_LEN;

  f32x4 o[2][4] = {};                  // O^T frag: row d = dn*16+lg*4+jj, col q = lc
  float mrow[2] = {-3.0e38f, -3.0e38f};
  float lsum[2] = {0.f, 0.f};          // per-lane partial; reduced in epilogue

  const int nt = (qt1 >> 1) + 1;       // 128-kv units
  const int nt0 = qt0 >> 1;            // chunk0 active while t <= nt0

  // STAGE: K 128x64 (4 issues) + V^T 64x128 (4 issues); 8 vmcnt ops/thread
#define STAGE(T, BSEL) do { \
    _Pragma("unroll") \
    for (int i_ = 0; i_ < 4; ++i_){ \
      const int row_ = i_ * 32 + (tid >> 3); \
      const int ch_  = tid & 7; \
      const int gc_  = ((ch_ ^ (row_ & 7)) << 4); \
      gload_lds16((const char*)(Kb + (size_t)((T) * 128 + row_) * 64) + gc_, \
                  (char*)lK[BSEL] + row_ * 128 + ch_ * 16); \
    } \
    _Pragma("unroll") \
    for (int i_ = 0; i_ < 4; ++i_){ \
      const int row_ = i_ * 16 + (tid >> 4); \
      const int ch_  = tid & 15; \
      const int gc_  = ((ch_ ^ (row_ & 15)) << 4); \
      gload_lds16((const char*)(Vb + (size_t)row_ * S_LEN + (T) * 128) + gc_, \
                  (char*)lV[BSEL] + row_ * 256 + ch_ * 16); \
    } \
  } while (0)

  STAGE(0, 0);

  for (int t = 0; t < nt; ++t){
    const int cur = t & 1;
    const bool act0 = (t <= nt0);
    if (t + 1 < nt){
      STAGE(t + 1, cur ^ 1);
      asm volatile("s_waitcnt vmcnt(8)" ::: "memory");   // tile-t loads landed
    } else {
      asm volatile("s_waitcnt vmcnt(0)" ::: "memory");
    }
    __builtin_amdgcn_s_barrier();

    // S^T = K Q^T : sv[c][nj][jj] = S[q=lc][k = t*128 + nj*16 + lg*4 + jj]
    f32x4 sv[2][8] = {};
    __builtin_amdgcn_s_setprio(1);
#pragma unroll
    for (int kk = 0; kk < 2; ++kk){
      short8 kf[8];
#pragma unroll
      for (int nj = 0; nj < 8; ++nj){
        const int row = nj * 16 + lc;
        const int cc = (kk * 4 + lg) ^ (row & 7);
        kf[nj] = *(const short8*)((const char*)lK[cur] + row * 128 + cc * 16);
      }
      if (act0)
#pragma unroll
        for (int nj = 0; nj < 8; ++nj)
          sv[0][nj] = __builtin_amdgcn_mfma_f32_16x16x32_bf16(kf[nj], qf[0][kk], sv[0][nj], 0, 0, 0);
#pragma unroll
      for (int nj = 0; nj < 8; ++nj)
        sv[1][nj] = __builtin_amdgcn_mfma_f32_16x16x32_bf16(kf[nj], qf[1][kk], sv[1][nj], 0, 0, 0);
    }
    __builtin_amdgcn_s_setprio(0);

    // per-chunk in-lane online softmax (exp2 domain) + pk-pack + shfl redistribution
    uint32_t pw[2][4][4];              // [chunk][kk2][word] -> PV B-frag
#pragma unroll
    for (int c = 0; c < 2; ++c){
      if (c == 0 && !act0) continue;
      const int qt = c ? qt1 : qt0;
      if (t == (qt >> 1)){             // unit containing the diagonal: mask k > q
        const int qloc = (qt & 1) * 64 + w * 16 + lc;
#pragma unroll
        for (int nj = 0; nj < 8; ++nj)
#pragma unroll
          for (int jj = 0; jj < 4; ++jj){
            const int kloc = nj * 16 + lg * 4 + jj;
            if (kloc > qloc) sv[c][nj][jj] = -3.0e38f;
          }
      }
      float mu = sv[c][0][0];
#pragma unroll
      for (int nj = 0; nj < 8; ++nj)
#pragma unroll
        for (int jj = 0; jj < 4; ++jj) mu = fmaxf(mu, sv[c][nj][jj]);
      mu = fmaxf(mu, __shfl_xor(mu, 16));
      mu = fmaxf(mu, __shfl_xor(mu, 32));
      // defer-max: only rescale when max grew past THR (log2 domain)
      if (!__all(mu <= mrow[c] + 11.54f)){
        const float mnew = fmaxf(mrow[c], mu);
        const float sf = __builtin_amdgcn_exp2f(mrow[c] - mnew);
        mrow[c] = mnew;
        lsum[c] *= sf;
#pragma unroll
        for (int dn = 0; dn < 4; ++dn)
#pragma unroll
          for (int jj = 0; jj < 4; ++jj) o[c][dn][jj] *= sf;
      }
      const float mcur = mrow[c];
      float ps = 0.f;
#pragma unroll
      for (int nj = 0; nj < 8; ++nj)
#pragma unroll
        for (int jj = 0; jj < 4; ++jj){
          const float pv = __builtin_amdgcn_exp2f(sv[c][nj][jj] - mcur);
          sv[c][nj][jj] = pv;
          ps += pv;
        }
      lsum[c] += ps;                   // per-lane partial (reduced at end)
      // pack p -> bf16 pairs; rx[nj] = (jj=0,1), ry[nj] = (jj=2,3)
      uint32_t rx[8], ry[8];
#pragma unroll
      for (int nj = 0; nj < 8; ++nj){
        rx[nj] = cvt_pk_bf16(sv[c][nj][0], sv[c][nj][1]);
        ry[nj] = cvt_pk_bf16(sv[c][nj][2], sv[c][nj][3]);
      }
      // redistribute: target (lg,lc) kk2 element e needs
      //   src lane (lg&1)*32 + (e>=4)*16 + lc, word rx/ry[kk2*2 + (lg>=2)]
      const int srcA = (lg & 1) * 32 + lc;
      const bool hi = (lg & 2) != 0;
#pragma unroll
      for (int kk2 = 0; kk2 < 4; ++kk2){
        uint32_t x0 = (uint32_t)__shfl((int)rx[kk2 * 2],     srcA);
        uint32_t x1 = (uint32_t)__shfl((int)rx[kk2 * 2 + 1], srcA);
        uint32_t y0 = (uint32_t)__shfl((int)ry[kk2 * 2],     srcA);
        uint32_t y1 = (uint32_t)__shfl((int)ry[kk2 * 2 + 1], srcA);
        pw[c][kk2][0] = hi ? x1 : x0;
        pw[c][kk2][1] = hi ? y1 : y0;
        x0 = (uint32_t)__shfl((int)rx[kk2 * 2],     srcA + 16);
        x1 = (uint32_t)__shfl((int)rx[kk2 * 2 + 1], srcA + 16);
        y0 = (uint32_t)__shfl((int)ry[kk2 * 2],     srcA + 16);
        y1 = (uint32_t)__shfl((int)ry[kk2 * 2 + 1], srcA + 16);
        pw[c][kk2][2] = hi ? x1 : x0;
        pw[c][kk2][3] = hi ? y1 : y0;
      }
    }

    // O^T += V^T P^T  (kv-dim 128 = 4 kk2 slices)
    __builtin_amdgcn_s_setprio(1);
#pragma unroll
    for (int kk2 = 0; kk2 < 4; ++kk2){
      short8 vf[4];
#pragma unroll
      for (int dn = 0; dn < 4; ++dn){
        const int row = dn * 16 + lc;
        const int cc = (kk2 * 4 + lg) ^ (row & 15);
        vf[dn] = *(const short8*)((const char*)lV[cur] + row * 256 + cc * 16);
      }
#pragma unroll
      for (int c = 0; c < 2; ++c){
        if (c == 0 && !act0) continue;
        u32x4 pwv = { pw[c][kk2][0], pw[c][kk2][1], pw[c][kk2][2], pw[c][kk2][3] };
        const short8 pb = __builtin_bit_cast(short8, pwv);
#pragma unroll
        for (int dn = 0; dn < 4; ++dn)
          o[c][dn] = __builtin_amdgcn_mfma_f32_16x16x32_bf16(vf[dn], pb, o[c][dn], 0, 0, 0);
      }
    }
    __builtin_amdgcn_s_setprio(0);
    __builtin_amdgcn_s_barrier();
  }
#undef STAGE

  // epilogue: reduce lsum partials, normalize, write Ao[b][s=q][h*64+d]
#pragma unroll
  for (int c = 0; c < 2; ++c){
    const int qt = c ? qt1 : qt0;
    float ls = lsum[c];
    ls += __shfl_xor(ls, 16);
    ls += __shfl_xor(ls, 32);
    const float inv = 1.f / ls;
    const int sq = qt * 64 + w * 16 + lc;
#pragma unroll
    for (int dn = 0; dn < 4; ++dn){
      uint2 pk;
      pk.x = cvt_pk_bf16(o[c][dn][0] * inv, o[c][dn][1] * inv);
      pk.y = cvt_pk_bf16(o[c][dn][2] * inv, o[c][dn][3] * inv);
      const int col = h * 64 + dn * 16 + lg * 4;
      *(uint2*)&Ao[(size_t)(b * S_LEN + sq) * 2048 + col] = pk;
    }
  }
}

// ---------------- launcher ----------------
extern "C" void kernel_launch(void* const* d_in, const int* in_sizes, int n_in,
                              void* d_out, int out_size, void* d_ws, size_t ws_size,
                              hipStream_t stream)
{
  const float* cosT = (const float*)d_in[0];
  const float* sinT = (const float*)d_in[1];
  const float* hs   = (const float*)d_in[2];
  const float* phs  = (const float*)d_in[3];
  const float* Wqkv = (const float*)d_in[4];
  const float* Wo   = (const float*)d_in[5];
  float* out = (float*)d_out;
  char* ws = (char*)d_ws;

  u16* hsB   = (u16*)(ws);               // 16,777,216 B (aliased as attn_out later)
  u16* WqkvB = (u16*)(ws + 16777216);    // 12,582,912 B
  u16* WoB   = (u16*)(ws + 29360128);    //  8,388,608 B
  u16* qkvB  = (u16*)(ws + 37748736);    // 25,165,824 B
  u16* Qb    = (u16*)(ws + 62914560);    // 16,777,216 B
  u16* Kb    = (u16*)(ws + 79691776);    //  4,194,304 B
  u16* VTb   = (u16*)(ws + 83886080);    //  4,194,304 B  (total 88,080,384 B)
  u16* Ao    = hsB;                      // hsB dead after GEMM1

  cvt_all<<<18432, 256, 0, stream>>>(hs, Wqkv, Wo, hsB, WqkvB, WoB);
  gemm_bt<0><<<dim3(24, 32), 256, 0, stream>>>(hsB, WqkvB, (void*)qkvB, 3072, 2048);
  rope_kernel<<<2560, 256, 0, stream>>>(qkvB, cosT, sinT, phs, Qb, Kb);
  vtrans<<<512, 256, 0, stream>>>(qkvB, VTb);
  attn_kernel<<<1024, 256, 0, stream>>>(Qb, Kb, VTb, Ao);
  gemm_bt<1><<<dim3(16, 32), 256, 0, stream>>>(Ao, WoB, (void*)out, 2048, 2048);
}